// Round 16
// baseline (391.982 us; speedup 1.0000x reference)
//
#include <hip/hip_runtime.h>
#include <cstdint>

// Transformer block: LN1 -> {QK GEMM, V^T GEMM} -> flash attn (swapped-QK,
// in-register softmax exp2-domain, permlane P re-layout) -> out-proj(+res)
// -> LN2 -> fc1(+GELU) -> fc2(+res). All matmuls bf16 MFMA, fp32 accum.
// R16: gemm256 quad->DOUBLE buffer (64 KB LDS -> 2 blocks/CU, 16 waves/CU)
// for cross-block stall overlap (m114); stage-after-compute, counted
// vwait(LPT), 2 barriers/tile. log2e folded into cvt4 Q-weight conversion.

using short8 = __attribute__((ext_vector_type(8))) short;
using f32x4  = __attribute__((ext_vector_type(4))) float;
using f32x16 = __attribute__((ext_vector_type(16))) float;

#define EMBED  1024
#define HIDDEN 4096
#define SEQ    2048
#define NTOK   8192   // 4*2048
#define LOG2E  1.4426950408889634f

__device__ __forceinline__ ushort f2bf(float x) {
  union { float f; uint32_t u; } v; v.f = x;
  uint32_t r = v.u + 0x7fffu + ((v.u >> 16) & 1u);   // RNE
  return (ushort)(r >> 16);
}

__device__ __forceinline__ uint32_t pkbf(float lo, float hi) {
  uint32_t r;
  asm("v_cvt_pk_bf16_f32 %0, %1, %2" : "=v"(r) : "v"(lo), "v"(hi));
  return r;
}

__device__ __forceinline__ void gload16(const void* g, void* l) {
  __builtin_amdgcn_global_load_lds((__attribute__((address_space(1))) void*)(g),
                                   (__attribute__((address_space(3))) void*)(l), 16, 0, 0);
}

template<int N> __device__ __forceinline__ void vwait() {
  asm volatile("s_waitcnt vmcnt(%0)" :: "n"(N) : "memory");
}
__device__ __forceinline__ void lgkm0() {
  asm volatile("s_waitcnt lgkmcnt(0)" ::: "memory");
}
__device__ __forceinline__ void fence_bar() {
  asm volatile("" ::: "memory");
  __builtin_amdgcn_s_barrier();
  asm volatile("" ::: "memory");
}

__device__ __forceinline__ f32x4 mfma16(short8 a, short8 b, f32x4 c) {
  return __builtin_amdgcn_mfma_f32_16x16x32_bf16(a, b, c, 0, 0, 0);
}
__device__ __forceinline__ f32x16 mfma32(short8 a, short8 b, f32x16 c) {
  return __builtin_amdgcn_mfma_f32_32x32x16_bf16(a, b, c, 0, 0, 0);
}
__device__ __forceinline__ f32x16 zero16() {
  f32x16 z = {0.f,0.f,0.f,0.f,0.f,0.f,0.f,0.f,0.f,0.f,0.f,0.f,0.f,0.f,0.f,0.f};
  return z;
}

// ---------------- fp32 -> bf16 weight conversion (all 4 weights, 1 launch) ----------------
// Q rows of qkv_w (flat j < 262144 float4s) pre-scaled by log2e for exp2 softmax.
__global__ __launch_bounds__(256) void cvt4_kernel(const float* __restrict__ s0, ushort* __restrict__ d0, int n0,
                                                   const float* __restrict__ s1, ushort* __restrict__ d1, int n1,
                                                   const float* __restrict__ s2, ushort* __restrict__ d2, int n2,
                                                   const float* __restrict__ s3, ushort* __restrict__ d3, int n3) {
  const int total = n0 + n1 + n2 + n3;
  for (int i = blockIdx.x * 256 + threadIdx.x; i < total; i += gridDim.x * 256) {
    const float* s; ushort* d; int j = i; float sc = 1.f;
    if (j < n0) { s = s0; d = d0; if (j < (EMBED * EMBED / 4)) sc = LOG2E; }
    else {
      j -= n0;
      if (j < n1) { s = s1; d = d1; }
      else {
        j -= n1;
        if (j < n2) { s = s2; d = d2; }
        else { j -= n2; s = s3; d = d3; }
      }
    }
    const float4 v = reinterpret_cast<const float4*>(s)[j];
    ushort4 o; o.x = f2bf(v.x * sc); o.y = f2bf(v.y * sc);
    o.z = f2bf(v.z * sc); o.w = f2bf(v.w * sc);
    reinterpret_cast<ushort4*>(d)[j] = o;
  }
}

// ---------------- LayerNorm (fp32 in, bf16 out) ----------------
__global__ __launch_bounds__(256) void ln_kernel(const float* __restrict__ x,
                                                 const float* __restrict__ g,
                                                 const float* __restrict__ b,
                                                 ushort* __restrict__ out) {
  const int row = blockIdx.x, tid = threadIdx.x;
  const float4 xv = reinterpret_cast<const float4*>(x + (size_t)row * EMBED)[tid];
  float s  = xv.x + xv.y + xv.z + xv.w;
  float s2 = xv.x*xv.x + xv.y*xv.y + xv.z*xv.z + xv.w*xv.w;
  #pragma unroll
  for (int off = 32; off >= 1; off >>= 1) { s += __shfl_xor(s, off); s2 += __shfl_xor(s2, off); }
  __shared__ float ps[4], ps2[4];
  if ((tid & 63) == 0) { ps[tid >> 6] = s; ps2[tid >> 6] = s2; }
  __syncthreads();
  s  = ps[0] + ps[1] + ps[2] + ps[3];
  s2 = ps2[0] + ps2[1] + ps2[2] + ps2[3];
  const float mu  = s * (1.f / EMBED);
  const float var = s2 * (1.f / EMBED) - mu * mu;
  const float rs  = rsqrtf(var + 1e-5f);
  const float4 gv = reinterpret_cast<const float4*>(g)[tid];
  const float4 bv = reinterpret_cast<const float4*>(b)[tid];
  ushort4 o;
  o.x = f2bf((xv.x - mu) * rs * gv.x + bv.x);
  o.y = f2bf((xv.y - mu) * rs * gv.y + bv.y);
  o.z = f2bf((xv.z - mu) * rs * gv.z + bv.z);
  o.w = f2bf((xv.w - mu) * rs * gv.w + bv.w);
  reinterpret_cast<ushort4*>(out + (size_t)row * EMBED)[tid] = o;
}

// ---------------- bf16 GEMM: C[M,N] = A[M,K] * B[N,K]^T (+epilogue) ----------------
// SQ=true: 256x256 tile (8 waves 2Mx4N). SQ=false: 256x128 tile (8 waves 4Mx2N).
// DOUBLE-buffered BK=32 (64/48 KB LDS -> 2 blocks/CU): per tile {read frags,
// MFMA, barrier, stage t+2 into cur buf, vwait(LPT) [t+1 resident], barrier}.
// Ledger: <=2*LPT outstanding; vwait(LPT) retires exactly t+1's loads (FIFO).
// WAR: staging into cur sits behind the barrier following all waves' reads.
// L2-locality partition: XCD p owns contiguous M-slice (or N-slice if gx<8).
template<int EPI, bool SQ>
__global__ __launch_bounds__(512) void gemm256(const ushort* __restrict__ A,
                                               const ushort* __restrict__ B,
                                               const float* __restrict__ bias,
                                               const float* __restrict__ res,
                                               ushort* __restrict__ outb,
                                               float* __restrict__ outf,
                                               int M, int N, int K, int gx) {
  constexpr int BN   = SQ ? 256 : 128;
  constexpr int MP   = SQ ? 8 : 4;          // 16-row m-positions per wave
  constexpr int NPH  = SQ ? 2 : 1;          // A-frag phases per K-tile
  constexpr int LPT  = SQ ? 4 : 3;          // gload16 rounds per tile per thread
  constexpr int NB   = LPT - 2;             // B staging rounds
  constexpr int ABUF = 256 * 32;            // ushorts
  constexpr int BBUF = BN * 32;
  __shared__ ushort lds[2][ABUF + BBUF];

  const int nwg = gridDim.x;                // nwg % 8 == 0 for all our shapes
  const int b0  = blockIdx.x;
  // locality partition (XCD = blockIdx % 8)
  const int p = b0 & 7, li = b0 >> 3;
  int mt, nt;
  if ((gx & 7) == 0) {                      // partition M across XCDs
    const int g = gx >> 3;                  // m-tiles per XCD
    mt = p * g + (li % g);                  // m fastest within XCD
    nt = li / g;
  } else {                                  // partition N across XCDs (gy%8==0)
    const int g = (nwg / gx) >> 3;          // n-tiles per XCD
    nt = p * g + (li % g);                  // n fastest within XCD
    mt = li / g;
  }
  const int m0 = mt * 256;
  const int n0 = nt * BN;

  const int tid = threadIdx.x, lane = tid & 63, wave = tid >> 6;
  const int wm = (SQ ? (wave >> 2) : (wave >> 1)) * (MP * 16);
  const int wn = (SQ ? (wave & 3) : (wave & 1)) * 64;
  const int l15 = lane & 15, l4 = lane >> 4;
  const int NT = K >> 5;                    // even for all our shapes

  // per-thread staging source pointers; advance +32 elems per staged tile
  const ushort* aSrc[2];
  const ushort* bSrc[NB];
  #pragma unroll
  for (int rd = 0; rd < 2; ++rd) {
    const int slot = rd * 512 + tid;
    const int r = slot >> 2;
    const int cs = (slot & 3) ^ ((r >> 1) & 3);
    aSrc[rd] = A + (size_t)(m0 + r) * K + cs * 8;
  }
  #pragma unroll
  for (int rd = 0; rd < NB; ++rd) {
    const int slot = rd * 512 + tid;
    const int r = slot >> 2;
    const int cs = (slot & 3) ^ ((r >> 1) & 3);
    bSrc[rd] = B + (size_t)(n0 + r) * K + cs * 8;
  }
  auto stageA = [&](int buf, int rd) { gload16(aSrc[rd], &lds[buf][(rd * 512 + tid) * 8]); };
  auto stageB = [&](int buf, int rd) { gload16(bSrc[rd], &lds[buf][ABUF + (rd * 512 + tid) * 8]); };
  auto advance = [&]() {
    #pragma unroll
    for (int rd = 0; rd < 2; ++rd) aSrc[rd] += 32;
    #pragma unroll
    for (int rd = 0; rd < NB; ++rd) bSrc[rd] += 32;
  };

  // hoisted fragment offsets (ushort units)
  int aOff[MP], bOff[4];
  #pragma unroll
  for (int i = 0; i < MP; ++i) {
    const int ra = wm + i * 16 + l15;
    aOff[i] = ra * 32 + ((l4 ^ ((ra >> 1) & 3)) * 8);
  }
  #pragma unroll
  for (int j = 0; j < 4; ++j) {
    const int rb = wn + j * 16 + l15;
    bOff[j] = rb * 32 + ((l4 ^ ((rb >> 1) & 3)) * 8);
  }

  // prologue: stage t0 -> buf0, t1 -> buf1
  #pragma unroll
  for (int t = 0; t < 2; ++t) {
    stageA(t, 0); stageA(t, 1);
    #pragma unroll
    for (int rd = 0; rd < NB; ++rd) stageB(t, rd);
    advance();
  }
  vwait<LPT>();                 // t0 resident; t1 in flight
  fence_bar();

  f32x4 acc[MP][4] = {};

  // one K-tile on buf q; stage t+2 into SAME buf after compute.
  // wsel: 0 -> vwait(LPT), 1 -> vwait(0), 2 -> none
  auto doTile = [&](int q, bool st, int wsel) {
    const ushort* bA = &lds[q][0];
    const ushort* bB = &lds[q][ABUF];
    short8 bf[4];
    #pragma unroll
    for (int j = 0; j < 4; ++j)
      bf[j] = *reinterpret_cast<const short8*>(&bB[bOff[j]]);
    #pragma unroll
    for (int ph = 0; ph < NPH; ++ph) {
      short8 af[4];
      #pragma unroll
      for (int i = 0; i < 4; ++i)
        af[i] = *reinterpret_cast<const short8*>(&bA[aOff[ph * 4 + i]]);
      __builtin_amdgcn_s_setprio(1);
      #pragma unroll
      for (int i = 0; i < 4; ++i)
        #pragma unroll
        for (int j = 0; j < 4; ++j)
          acc[ph * 4 + i][j] = mfma16(af[i], bf[j], acc[ph * 4 + i][j]);
      __builtin_amdgcn_s_setprio(0);
    }
    fence_bar();                // all waves done reading buf[q]
    if (st) {
      stageA(q, 0); stageA(q, 1);
      #pragma unroll
      for (int rd = 0; rd < NB; ++rd) stageB(q, rd);
      advance();
    }
    if (wsel == 0)      vwait<LPT>();   // t+1 (other buf) resident
    else if (wsel == 1) vwait<0>();
    fence_bar();
  };

  for (int u = 0; u < NT - 2; u += 2) {
    doTile(0, true, 0);
    doTile(1, (u + 1 < NT - 2), (u + 1 == NT - 2) ? 1 : 0);
  }
  doTile(0, false, 1);          // tile NT-2 (even parity; NT even)
  doTile(1, false, 2);          // tile NT-1

  #pragma unroll
  for (int i = 0; i < MP; ++i)
    #pragma unroll
    for (int j = 0; j < 4; ++j)
      #pragma unroll
      for (int r = 0; r < 4; ++r) {
        const int row = m0 + wm + i * 16 + l4 * 4 + r;
        const int col = n0 + wn + j * 16 + l15;
        const size_t idx = (size_t)row * N + col;
        float v = acc[i][j][r];
        if constexpr (EPI == 0) {
          outb[idx] = f2bf(v);
        } else if constexpr (EPI == 1) {
          outf[idx] = v + bias[col] + res[idx];
        } else {
          v += bias[col];
          v = 0.5f * v * (1.f + erff(v * 0.70710678118654752f));
          outb[idx] = f2bf(v);
        }
      }
}

// ---------------- flash attention, swapped-QK, exp2-domain softmax ----------------
// grid (B*H=64, SEQ/256=8), block 512 (8 waves). Wave: 32 q rows.
// qk: [8192][2048] bf16 (q*log2e at col h*64, k at col 1024+h*64).
// vt: [1024][8192] bf16. P = exp2(S'-m') via raw v_exp_f32. 16 waves/CU.
#define KVB 64
#define NTT (SEQ / KVB)

__global__ __launch_bounds__(512, 4) void attn_kernel(const ushort* __restrict__ qk,
                                                      const ushort* __restrict__ vt,
                                                      ushort* __restrict__ outp) {
  const int tid = threadIdx.x, lane = tid & 63, wq = tid >> 6;   // wq 0..7
  const int hi = lane >> 5, lo = lane & 31;
  const int b = blockIdx.x >> 4, h = blockIdx.x & 15;
  const int q0 = blockIdx.y * 256;

  __shared__ ushort sK[2][64 * 64];
  __shared__ ushort sVt[2][64 * 64];
  __shared__ float sBc[8][32];

  // Q fragments (B-operand): wave covers q rows q0 + wq*32 .. +31 (lane q = lo)
  short8 qf[4];
  #pragma unroll
  for (int kc = 0; kc < 4; ++kc)
    qf[kc] = *reinterpret_cast<const short8*>(
        qk + (size_t)(b * SEQ + q0 + wq * 32 + lo) * 2048 + h * 64 + kc * 16 + hi * 8);

  auto STAGE = [&](int bb, int kt) {
    const int r = tid >> 3;
    const int c = (tid & 7) ^ (r & 7);            // inverse-swizzled source chunk
    gload16(qk + (size_t)(b * SEQ + kt + r) * 2048 + 1024 + h * 64 + c * 8,
            &sK[bb][wq * 64 * 8]);                // wave-uniform dest + lane*16B
    gload16(vt + (size_t)(h * 64 + r) * 8192 + b * SEQ + kt + c * 8,
            &sVt[bb][wq * 64 * 8]);
  };

  f32x16 acc[2];
  acc[0] = zero16(); acc[1] = zero16();
  float mst = -1e30f, lst = 0.f;

  STAGE(0, 0);
  for (int t = 0; t < NTT; ++t) {
    const int cur = t & 1;
    __syncthreads();                       // staged buf[cur] ready; buf[cur^1] free
    if (t + 1 < NTT) STAGE(cur ^ 1, (t + 1) * KVB);

    // K fragments (A-operand): row kv, swizzled b128 reads
    short8 kf[2][4];
    #pragma unroll
    for (int kvb = 0; kvb < 2; ++kvb)
      #pragma unroll
      for (int kc = 0; kc < 4; ++kc) {
        const int row = kvb * 32 + lo, ch = kc * 2 + hi;
        kf[kvb][kc] = *reinterpret_cast<const short8*>(
            &sK[cur][(row * 8 + (ch ^ (row & 7))) * 8]);
      }

    // S'^T = K * (Q*log2e)^T : lane holds q=lo, kv rows in regs (exp2 domain)
    f32x16 st[2];
    #pragma unroll
    for (int kvb = 0; kvb < 2; ++kvb) {
      f32x16 tq = zero16();
      tq = mfma32(kf[kvb][0], qf[0], tq);
      tq = mfma32(kf[kvb][1], qf[1], tq);
      tq = mfma32(kf[kvb][2], qf[2], tq);
      tq = mfma32(kf[kvb][3], qf[3], tq);
      st[kvb] = tq;
    }
    // row max: pairwise combine + max3-fusable triple chain
    f32x16 mm;
    #pragma unroll
    for (int r = 0; r < 16; ++r) mm[r] = fmaxf(st[0][r], st[1][r]);
    float pm = fmaxf(fmaxf(mm[0], mm[1]), mm[2]);
    pm = fmaxf(fmaxf(pm, mm[3]), mm[4]);
    pm = fmaxf(fmaxf(pm, mm[5]), mm[6]);
    pm = fmaxf(fmaxf(pm, mm[7]), mm[8]);
    pm = fmaxf(fmaxf(pm, mm[9]), mm[10]);
    pm = fmaxf(fmaxf(pm, mm[11]), mm[12]);
    pm = fmaxf(fmaxf(pm, mm[13]), mm[14]);
    pm = fmaxf(pm, mm[15]);
    pm = fmaxf(pm, __shfl_xor(pm, 32));
    // defer-max (exp2 domain): 8 nats = 11.54 bits
    if (__any(pm > mst + 11.54f)) {
      const float mn = fmaxf(mst, pm);
      const float al = __builtin_amdgcn_exp2f(mst - mn);
      mst = mn; lst *= al;
      sBc[wq][lo] = al;
      lgkm0();
      #pragma unroll
      for (int g = 0; g < 4; ++g) {
        const f32x4 a4 = *reinterpret_cast<const f32x4*>(&sBc[wq][g * 8 + hi * 4]);
        #pragma unroll
        for (int j = 0; j < 4; ++j) {
          acc[0][g * 4 + j] *= a4[j];
          acc[1][g * 4 + j] *= a4[j];
        }
      }
    }
    // P = exp2(S' - m'), row sum  (raw v_exp_f32, no libcall)
    #pragma unroll
    for (int kvb = 0; kvb < 2; ++kvb)
      #pragma unroll
      for (int r = 0; r < 16; ++r)
        st[kvb][r] = __builtin_amdgcn_exp2f(st[kvb][r] - mst);
    {
      const f32x16 sv = st[0] + st[1];
      float sum = ((sv[0] + sv[1]) + (sv[2] + sv[3])) + ((sv[4] + sv[5]) + (sv[6] + sv[7]))
                + ((sv[8] + sv[9]) + (sv[10] + sv[11])) + ((sv[12] + sv[13]) + (sv[14] + sv[15]));
      sum += __shfl_xor(sum, 32);
      lst += sum;
    }
    // pack P -> bf16 A-fragments via cvt_pk + permlane32_swap
    short8 pa[4];
    #pragma unroll
    for (int kvb = 0; kvb < 2; ++kvb)
      #pragma unroll
      for (int f = 0; f < 2; ++f) {
        uint32_t wa = pkbf(st[kvb][f * 8 + 0], st[kvb][f * 8 + 1]);
        uint32_t wb = pkbf(st[kvb][f * 8 + 2], st[kvb][f * 8 + 3]);
        uint32_t wc = pkbf(st[kvb][f * 8 + 4], st[kvb][f * 8 + 5]);
        uint32_t wd = pkbf(st[kvb][f * 8 + 6], st[kvb][f * 8 + 7]);
        asm volatile("v_permlane32_swap_b32 %0, %1" : "+v"(wa), "+v"(wc));
        asm volatile("v_permlane32_swap_b32 %0, %1" : "+v"(wb), "+v"(wd));
        union { uint32_t w[4]; short8 v; } u;
        u.w[0] = wa; u.w[1] = wb; u.w[2] = wc; u.w[3] = wd;
        pa[kvb * 2 + f] = u.v;
      }

    // O += P V  (B-operand = V^T rows d)
    #pragma unroll
    for (int db = 0; db < 2; ++db) {
      short8 vb[4];
      #pragma unroll
      for (int k4 = 0; k4 < 4; ++k4) {
        const int row = db * 32 + lo, ch = k4 * 2 + hi;
        vb[k4] = *reinterpret_cast<const short8*>(
            &sVt[cur][(row * 8 + (ch ^ (row & 7))) * 8]);
      }
      acc[db] = mfma32(pa[0], vb[0], acc[db]);
      acc[db] = mfma32(pa[1], vb[1], acc[db]);
      acc[db] = mfma32(pa[2], vb[2], acc[db]);
      acc[db] = mfma32(pa[3], vb[3], acc[db]);
    }
  }

  // epilogue: O /= l, write bf16 [8192][1024]
  sBc[wq][lo] = 1.f / lst;
  lgkm0();
  #pragma unroll
  for (int g = 0; g < 4; ++g) {
    const f32x4 r4 = *reinterpret_cast<const f32x4*>(&sBc[wq][g * 8 + hi * 4]);
    #pragma unroll
    for (int j = 0; j < 4; ++j) {
      const int qrow = q0 + wq * 32 + g * 8 + hi * 4 + j;
      #pragma unroll
      for (int db = 0; db < 2; ++db)
        outp[(size_t)(b * SEQ + qrow) * EMBED + h * 64 + db * 32 + lo] =
            f2bf(acc[db][g * 4 + j] * r4[j]);
    }
  }
}

// ---------------- launch ----------------
extern "C" void kernel_launch(void* const* d_in, const int* in_sizes, int n_in,
                              void* d_out, int out_size, void* d_ws, size_t ws_size,
                              hipStream_t stream) {
  const float* x     = (const float*)d_in[0];
  const float* ln1_g = (const float*)d_in[1];
  const float* ln1_b = (const float*)d_in[2];
  const float* qkv_w = (const float*)d_in[3];
  const float* out_w = (const float*)d_in[4];
  const float* out_b = (const float*)d_in[5];
  const float* ln2_g = (const float*)d_in[6];
  const float* ln2_b = (const float*)d_in[7];
  const float* fc1_w = (const float*)d_in[8];
  const float* fc1_b = (const float*)d_in[9];
  const float* fc2_w = (const float*)d_in[10];
  const float* fc2_b = (const float*)d_in[11];
  float* out = (float*)d_out;
  char* ws = (char*)d_ws;

  // workspace layout (bytes)
  ushort* qkvw = (ushort*)(ws);                                   //  6291456
  ushort* outw = (ushort*)(ws + 6291456);                         //  2097152
  ushort* fc1w = (ushort*)(ws + 8388608);                         //  8388608
  ushort* fc2w = (ushort*)(ws + 16777216);                        //  8388608
  float*  x1   = (float*) (ws + 25165824);                        // 33554432
  ushort* hbuf = (ushort*)(ws + 58720256);                        // 16777216
  ushort* qkbuf= (ushort*)(ws + 75497472);                        // 33554432  [8192][2048]
  ushort* vtbuf= (ushort*)(ws + 109051904);                       // 16777216  [1024][8192]
  ushort* obuf = (ushort*)(ws + 125829120);                       // 16777216
  ushort* gbuf = qkbuf;  // gelu buf [8192][4096] reuses qk+vt+o regions (64 MiB)

  // all four weight conversions in one launch (Q rows pre-scaled by log2e)
  cvt4_kernel<<<2048, 256, 0, stream>>>(qkv_w, qkvw, 3 * EMBED * EMBED / 4,
                                        out_w, outw, EMBED * EMBED / 4,
                                        fc1_w, fc1w, HIDDEN * EMBED / 4,
                                        fc2_w, fc2w, EMBED * HIDDEN / 4);

  ln_kernel<<<NTOK, 256, 0, stream>>>(x, ln1_g, ln1_b, hbuf);
  // QK: [8192][2048] = hbuf * Wqk'^T  (Q cols already log2e-scaled)
  gemm256<0, true><<<256, 512, 0, stream>>>(hbuf, qkvw, nullptr, nullptr,
                                            qkbuf, nullptr, NTOK, 2 * EMBED, EMBED, 32);
  // V^T: [1024][8192] = Wv * hbuf^T   (256x128 tiles, N-partitioned)
  gemm256<0, false><<<256, 512, 0, stream>>>(qkvw + 2048 * 1024, hbuf, nullptr, nullptr,
                                             vtbuf, nullptr, EMBED, NTOK, EMBED, 4);
  attn_kernel<<<dim3(64, 8), 512, 0, stream>>>(qkbuf, vtbuf, obuf);
  // out-proj
  gemm256<1, false><<<256, 512, 0, stream>>>(obuf, outw, out_b, x,
                                             nullptr, x1, NTOK, EMBED, EMBED, 32);
  ln_kernel<<<NTOK, 256, 0, stream>>>(x1, ln2_g, ln2_b, hbuf);
  // fc1
  gemm256<2, true><<<512, 512, 0, stream>>>(hbuf, fc1w, fc1_b, nullptr,
                                            gbuf, nullptr, NTOK, HIDDEN, EMBED, 32);
  // fc2
  gemm256<1, false><<<256, 512, 0, stream>>>(gbuf, fc2w, fc2_b, x1,
                                             nullptr, out, NTOK, EMBED, HIDDEN, 32);
}

// Round 17
// 380.801 us; speedup vs baseline: 1.0294x; 1.0294x over previous
//
#include <hip/hip_runtime.h>
#include <cstdint>

// Transformer block: LN1 -> {QK GEMM, V^T GEMM} -> flash attn (swapped-QK,
// in-register softmax, permlane P re-layout) -> out-proj(+res) -> LN2
// -> fc1(+GELU) -> fc2(+res). All matmuls bf16 MFMA, fp32 accum.
// R17 = R15 verbatim (best measured: 379.0 us). gemm256 quad-buffer +
// L2-locality partition; 8-wave attn with exp2-domain softmax via
// __builtin_amdgcn_exp2f; Q cols scaled by log2e in QK epilogue (EPI 3).

using short8 = __attribute__((ext_vector_type(8))) short;
using f32x4  = __attribute__((ext_vector_type(4))) float;
using f32x16 = __attribute__((ext_vector_type(16))) float;

#define EMBED  1024
#define HIDDEN 4096
#define SEQ    2048
#define NTOK   8192   // 4*2048
#define LOG2E  1.4426950408889634f

__device__ __forceinline__ ushort f2bf(float x) {
  union { float f; uint32_t u; } v; v.f = x;
  uint32_t r = v.u + 0x7fffu + ((v.u >> 16) & 1u);   // RNE
  return (ushort)(r >> 16);
}

__device__ __forceinline__ uint32_t pkbf(float lo, float hi) {
  uint32_t r;
  asm("v_cvt_pk_bf16_f32 %0, %1, %2" : "=v"(r) : "v"(lo), "v"(hi));
  return r;
}

__device__ __forceinline__ void gload16(const void* g, void* l) {
  __builtin_amdgcn_global_load_lds((__attribute__((address_space(1))) void*)(g),
                                   (__attribute__((address_space(3))) void*)(l), 16, 0, 0);
}

template<int N> __device__ __forceinline__ void vwait() {
  asm volatile("s_waitcnt vmcnt(%0)" :: "n"(N) : "memory");
}
__device__ __forceinline__ void lgkm0() {
  asm volatile("s_waitcnt lgkmcnt(0)" ::: "memory");
}
__device__ __forceinline__ void fence_bar() {
  asm volatile("" ::: "memory");
  __builtin_amdgcn_s_barrier();
  asm volatile("" ::: "memory");
}

__device__ __forceinline__ f32x4 mfma16(short8 a, short8 b, f32x4 c) {
  return __builtin_amdgcn_mfma_f32_16x16x32_bf16(a, b, c, 0, 0, 0);
}
__device__ __forceinline__ f32x16 mfma32(short8 a, short8 b, f32x16 c) {
  return __builtin_amdgcn_mfma_f32_32x32x16_bf16(a, b, c, 0, 0, 0);
}
__device__ __forceinline__ f32x16 zero16() {
  f32x16 z = {0.f,0.f,0.f,0.f,0.f,0.f,0.f,0.f,0.f,0.f,0.f,0.f,0.f,0.f,0.f,0.f};
  return z;
}

// ---------------- fp32 -> bf16 weight conversion (all 4 weights, 1 launch) ----------------
__global__ __launch_bounds__(256) void cvt4_kernel(const float* __restrict__ s0, ushort* __restrict__ d0, int n0,
                                                   const float* __restrict__ s1, ushort* __restrict__ d1, int n1,
                                                   const float* __restrict__ s2, ushort* __restrict__ d2, int n2,
                                                   const float* __restrict__ s3, ushort* __restrict__ d3, int n3) {
  const int total = n0 + n1 + n2 + n3;
  for (int i = blockIdx.x * 256 + threadIdx.x; i < total; i += gridDim.x * 256) {
    const float* s; ushort* d; int j = i;
    if (j < n0) { s = s0; d = d0; }
    else {
      j -= n0;
      if (j < n1) { s = s1; d = d1; }
      else {
        j -= n1;
        if (j < n2) { s = s2; d = d2; }
        else { j -= n2; s = s3; d = d3; }
      }
    }
    const float4 v = reinterpret_cast<const float4*>(s)[j];
    ushort4 o; o.x = f2bf(v.x); o.y = f2bf(v.y); o.z = f2bf(v.z); o.w = f2bf(v.w);
    reinterpret_cast<ushort4*>(d)[j] = o;
  }
}

// ---------------- LayerNorm (fp32 in, bf16 out) ----------------
__global__ __launch_bounds__(256) void ln_kernel(const float* __restrict__ x,
                                                 const float* __restrict__ g,
                                                 const float* __restrict__ b,
                                                 ushort* __restrict__ out) {
  const int row = blockIdx.x, tid = threadIdx.x;
  const float4 xv = reinterpret_cast<const float4*>(x + (size_t)row * EMBED)[tid];
  float s  = xv.x + xv.y + xv.z + xv.w;
  float s2 = xv.x*xv.x + xv.y*xv.y + xv.z*xv.z + xv.w*xv.w;
  #pragma unroll
  for (int off = 32; off >= 1; off >>= 1) { s += __shfl_xor(s, off); s2 += __shfl_xor(s2, off); }
  __shared__ float ps[4], ps2[4];
  if ((tid & 63) == 0) { ps[tid >> 6] = s; ps2[tid >> 6] = s2; }
  __syncthreads();
  s  = ps[0] + ps[1] + ps[2] + ps[3];
  s2 = ps2[0] + ps2[1] + ps2[2] + ps2[3];
  const float mu  = s * (1.f / EMBED);
  const float var = s2 * (1.f / EMBED) - mu * mu;
  const float rs  = rsqrtf(var + 1e-5f);
  const float4 gv = reinterpret_cast<const float4*>(g)[tid];
  const float4 bv = reinterpret_cast<const float4*>(b)[tid];
  ushort4 o;
  o.x = f2bf((xv.x - mu) * rs * gv.x + bv.x);
  o.y = f2bf((xv.y - mu) * rs * gv.y + bv.y);
  o.z = f2bf((xv.z - mu) * rs * gv.z + bv.z);
  o.w = f2bf((xv.w - mu) * rs * gv.w + bv.w);
  reinterpret_cast<ushort4*>(out + (size_t)row * EMBED)[tid] = o;
}

// ---------------- bf16 GEMM: C[M,N] = A[M,K] * B[N,K]^T (+epilogue) ----------------
// SQ=true: 256x256 tile (8 waves 2Mx4N). SQ=false: 256x128 tile (8 waves 4Mx2N).
// Quad-buffered BK=32 tiles; stage tile u+3 during tile u; counted vmcnt; x4 unroll.
// L2-locality partition: XCD p owns contiguous M-slice (or N-slice if gx<8).
// EPI: 0 bf16 | 1 fp32+bias+res | 2 bf16 gelu(acc+bias) | 3 bf16, cols<1024 * log2e
template<int EPI, bool SQ>
__global__ __launch_bounds__(512) void gemm256(const ushort* __restrict__ A,
                                               const ushort* __restrict__ B,
                                               const float* __restrict__ bias,
                                               const float* __restrict__ res,
                                               ushort* __restrict__ outb,
                                               float* __restrict__ outf,
                                               int M, int N, int K, int gx) {
  constexpr int BN   = SQ ? 256 : 128;
  constexpr int MP   = SQ ? 8 : 4;          // 16-row m-positions per wave
  constexpr int NPH  = SQ ? 2 : 1;          // phases per K-tile
  constexpr int LPT  = SQ ? 4 : 3;          // gload16 rounds per tile per thread
  constexpr int NB   = LPT - 2;             // B staging rounds
  constexpr int ABUF = 256 * 32;            // ushorts
  constexpr int BBUF = BN * 32;
  __shared__ ushort lds[4][ABUF + BBUF];

  const int nwg = gridDim.x;                // nwg % 8 == 0 for all our shapes
  const int b0  = blockIdx.x;
  // locality partition (XCD = blockIdx % 8)
  const int p = b0 & 7, li = b0 >> 3;
  int mt, nt;
  if ((gx & 7) == 0) {                      // partition M across XCDs
    const int g = gx >> 3;                  // m-tiles per XCD
    mt = p * g + (li % g);                  // m fastest within XCD
    nt = li / g;
  } else {                                  // partition N across XCDs (gy%8==0)
    const int g = (nwg / gx) >> 3;          // n-tiles per XCD
    nt = p * g + (li % g);                  // n fastest within XCD
    mt = li / g;
  }
  const int m0 = mt * 256;
  const int n0 = nt * BN;

  const int tid = threadIdx.x, lane = tid & 63, wave = tid >> 6;
  const int wm = (SQ ? (wave >> 2) : (wave >> 1)) * (MP * 16);
  const int wn = (SQ ? (wave & 3) : (wave & 1)) * 64;
  const int l15 = lane & 15, l4 = lane >> 4;
  const int NT = K >> 5;                    // divisible by 4 for all our shapes

  // per-thread staging source pointers; advance +32 elems per staged tile
  const ushort* aSrc[2];
  const ushort* bSrc[NB];
  #pragma unroll
  for (int rd = 0; rd < 2; ++rd) {
    const int slot = rd * 512 + tid;
    const int r = slot >> 2;
    const int cs = (slot & 3) ^ ((r >> 1) & 3);
    aSrc[rd] = A + (size_t)(m0 + r) * K + cs * 8;
  }
  #pragma unroll
  for (int rd = 0; rd < NB; ++rd) {
    const int slot = rd * 512 + tid;
    const int r = slot >> 2;
    const int cs = (slot & 3) ^ ((r >> 1) & 3);
    bSrc[rd] = B + (size_t)(n0 + r) * K + cs * 8;
  }
  auto stageA = [&](int buf, int rd) { gload16(aSrc[rd], &lds[buf][(rd * 512 + tid) * 8]); };
  auto stageB = [&](int buf, int rd) { gload16(bSrc[rd], &lds[buf][ABUF + (rd * 512 + tid) * 8]); };
  auto advance = [&]() {
    #pragma unroll
    for (int rd = 0; rd < 2; ++rd) aSrc[rd] += 32;
    #pragma unroll
    for (int rd = 0; rd < NB; ++rd) bSrc[rd] += 32;
  };

  // prologue: stage tiles 0..2 into bufs 0..2
  #pragma unroll
  for (int t = 0; t < 3; ++t) {
    stageA(t, 0); stageA(t, 1);
    #pragma unroll
    for (int rd = 0; rd < NB; ++rd) stageB(t, rd);
    advance();
  }
  vwait<2 * LPT>();               // tile 0 resident; 2 tiles stay in flight
  fence_bar();

  f32x4 acc[MP][4] = {};

  // one K-tile; q = buffer index (compile-time at every call site),
  // st = stage tile u+3, wsel: 0 -> vwait(2LPT), 1 -> vwait(LPT), 2 -> vwait(0), 3 -> none
  auto doTile = [&](int q, bool st, int wsel) {
    const ushort* bA = &lds[q][0];
    const ushort* bB = &lds[q][ABUF];
    const int sbuf = (q + 3) & 3;
    short8 bf[4];
    #pragma unroll
    for (int j = 0; j < 4; ++j) {
      const int rb = wn + j * 16 + l15;
      bf[j] = *reinterpret_cast<const short8*>(&bB[rb * 32 + ((l4 ^ ((rb >> 1) & 3)) * 8)]);
    }
    #pragma unroll
    for (int ph = 0; ph < NPH; ++ph) {
      short8 af[4];
      #pragma unroll
      for (int i = 0; i < 4; ++i) {
        const int ra = wm + (ph * 4 + i) * 16 + l15;
        af[i] = *reinterpret_cast<const short8*>(&bA[ra * 32 + ((l4 ^ ((ra >> 1) & 3)) * 8)]);
      }
      if (st) {
        if constexpr (SQ) {
          if (ph == 0) { stageA(sbuf, 0); stageA(sbuf, 1); }
          else         { stageB(sbuf, 0); stageB(sbuf, 1); }
        } else {
          stageA(sbuf, 0); stageA(sbuf, 1); stageB(sbuf, 0);
        }
      }
      fence_bar();
      __builtin_amdgcn_s_setprio(1);
      #pragma unroll
      for (int i = 0; i < 4; ++i)
        #pragma unroll
        for (int j = 0; j < 4; ++j)
          acc[ph * 4 + i][j] = mfma16(af[i], bf[j], acc[ph * 4 + i][j]);
      __builtin_amdgcn_s_setprio(0);
      if (ph == NPH - 1) {        // tile boundary: next tile must be resident
        if (st) advance();
        if (wsel == 0)      vwait<2 * LPT>();
        else if (wsel == 1) vwait<LPT>();
        else if (wsel == 2) vwait<0>();
      }
      fence_bar();
    }
  };

  for (int u0 = 0; u0 < NT - 4; u0 += 4) {
    doTile(0, true, 0); doTile(1, true, 0); doTile(2, true, 0); doTile(3, true, 0);
  }
  // tail: u = NT-4 .. NT-1
  doTile(0, true, 0); doTile(1, false, 1); doTile(2, false, 2); doTile(3, false, 3);

  #pragma unroll
  for (int i = 0; i < MP; ++i)
    #pragma unroll
    for (int j = 0; j < 4; ++j)
      #pragma unroll
      for (int r = 0; r < 4; ++r) {
        const int row = m0 + wm + i * 16 + l4 * 4 + r;
        const int col = n0 + wn + j * 16 + l15;
        const size_t idx = (size_t)row * N + col;
        float v = acc[i][j][r];
        if constexpr (EPI == 0) {
          outb[idx] = f2bf(v);
        } else if constexpr (EPI == 1) {
          outf[idx] = v + bias[col] + res[idx];
        } else if constexpr (EPI == 2) {
          v += bias[col];
          v = 0.5f * v * (1.f + erff(v * 0.70710678118654752f));
          outb[idx] = f2bf(v);
        } else {
          // EPI 3: scale Q columns (col < 1024) by log2e for exp2-domain softmax
          outb[idx] = f2bf((col < 1024) ? v * LOG2E : v);
        }
      }
}

// ---------------- flash attention, swapped-QK, exp2-domain softmax ----------------
// grid (B*H=64, SEQ/256=8), block 512 (8 waves). Wave: 32 q rows.
// qk: [8192][2048] bf16 (q*log2e at col h*64, k at col 1024+h*64).
// vt: [1024][8192] bf16. S' = S*log2e -> P = exp2(S'-m') via raw v_exp_f32.
// No 1/sqrt(d) scaling (per reference). 16 waves/CU.
#define KVB 64
#define NTT (SEQ / KVB)

__global__ __launch_bounds__(512, 4) void attn_kernel(const ushort* __restrict__ qk,
                                                      const ushort* __restrict__ vt,
                                                      ushort* __restrict__ outp) {
  const int tid = threadIdx.x, lane = tid & 63, wq = tid >> 6;   // wq 0..7
  const int hi = lane >> 5, lo = lane & 31;
  const int b = blockIdx.x >> 4, h = blockIdx.x & 15;
  const int q0 = blockIdx.y * 256;

  __shared__ ushort sK[2][64 * 64];
  __shared__ ushort sVt[2][64 * 64];
  __shared__ float sBc[8][32];

  // Q fragments (B-operand): wave covers q rows q0 + wq*32 .. +31 (lane q = lo)
  short8 qf[4];
  #pragma unroll
  for (int kc = 0; kc < 4; ++kc)
    qf[kc] = *reinterpret_cast<const short8*>(
        qk + (size_t)(b * SEQ + q0 + wq * 32 + lo) * 2048 + h * 64 + kc * 16 + hi * 8);

  auto STAGE = [&](int bb, int kt) {
    const int r = tid >> 3;
    const int c = (tid & 7) ^ (r & 7);            // inverse-swizzled source chunk
    gload16(qk + (size_t)(b * SEQ + kt + r) * 2048 + 1024 + h * 64 + c * 8,
            &sK[bb][wq * 64 * 8]);                // wave-uniform dest + lane*16B
    gload16(vt + (size_t)(h * 64 + r) * 8192 + b * SEQ + kt + c * 8,
            &sVt[bb][wq * 64 * 8]);
  };

  f32x16 acc[2];
  acc[0] = zero16(); acc[1] = zero16();
  float mst = -1e30f, lst = 0.f;

  STAGE(0, 0);
  for (int t = 0; t < NTT; ++t) {
    const int cur = t & 1;
    __syncthreads();                       // staged buf[cur] ready; buf[cur^1] free
    if (t + 1 < NTT) STAGE(cur ^ 1, (t + 1) * KVB);

    // K fragments (A-operand): row kv, swizzled b128 reads
    short8 kf[2][4];
    #pragma unroll
    for (int kvb = 0; kvb < 2; ++kvb)
      #pragma unroll
      for (int kc = 0; kc < 4; ++kc) {
        const int row = kvb * 32 + lo, ch = kc * 2 + hi;
        kf[kvb][kc] = *reinterpret_cast<const short8*>(
            &sK[cur][(row * 8 + (ch ^ (row & 7))) * 8]);
      }

    // S'^T = K * (Q*log2e)^T : lane holds q=lo, kv rows in regs (exp2 domain)
    f32x16 st[2];
    #pragma unroll
    for (int kvb = 0; kvb < 2; ++kvb) {
      f32x16 tq = zero16();
      tq = mfma32(kf[kvb][0], qf[0], tq);
      tq = mfma32(kf[kvb][1], qf[1], tq);
      tq = mfma32(kf[kvb][2], qf[2], tq);
      tq = mfma32(kf[kvb][3], qf[3], tq);
      st[kvb] = tq;
    }
    // row max: pairwise combine + max3-fusable triple chain
    f32x16 mm;
    #pragma unroll
    for (int r = 0; r < 16; ++r) mm[r] = fmaxf(st[0][r], st[1][r]);
    float pm = fmaxf(fmaxf(mm[0], mm[1]), mm[2]);
    pm = fmaxf(fmaxf(pm, mm[3]), mm[4]);
    pm = fmaxf(fmaxf(pm, mm[5]), mm[6]);
    pm = fmaxf(fmaxf(pm, mm[7]), mm[8]);
    pm = fmaxf(fmaxf(pm, mm[9]), mm[10]);
    pm = fmaxf(fmaxf(pm, mm[11]), mm[12]);
    pm = fmaxf(fmaxf(pm, mm[13]), mm[14]);
    pm = fmaxf(pm, mm[15]);
    pm = fmaxf(pm, __shfl_xor(pm, 32));
    // defer-max (exp2 domain): 8 nats = 11.54 bits
    if (__any(pm > mst + 11.54f)) {
      const float mn = fmaxf(mst, pm);
      const float al = __builtin_amdgcn_exp2f(mst - mn);
      mst = mn; lst *= al;
      sBc[wq][lo] = al;
      lgkm0();
      #pragma unroll
      for (int g = 0; g < 4; ++g) {
        const f32x4 a4 = *reinterpret_cast<const f32x4*>(&sBc[wq][g * 8 + hi * 4]);
        #pragma unroll
        for (int j = 0; j < 4; ++j) {
          acc[0][g * 4 + j] *= a4[j];
          acc[1][g * 4 + j] *= a4[j];
        }
      }
    }
    // P = exp2(S' - m'), row sum  (raw v_exp_f32, no libcall, no pre-mul)
    #pragma unroll
    for (int kvb = 0; kvb < 2; ++kvb)
      #pragma unroll
      for (int r = 0; r < 16; ++r)
        st[kvb][r] = __builtin_amdgcn_exp2f(st[kvb][r] - mst);
    {
      const f32x16 sv = st[0] + st[1];
      float sum = ((sv[0] + sv[1]) + (sv[2] + sv[3])) + ((sv[4] + sv[5]) + (sv[6] + sv[7]))
                + ((sv[8] + sv[9]) + (sv[10] + sv[11])) + ((sv[12] + sv[13]) + (sv[14] + sv[15]));
      sum += __shfl_xor(sum, 32);
      lst += sum;
    }
    // pack P -> bf16 A-fragments via cvt_pk + permlane32_swap
    short8 pa[4];
    #pragma unroll
    for (int kvb = 0; kvb < 2; ++kvb)
      #pragma unroll
      for (int f = 0; f < 2; ++f) {
        uint32_t wa = pkbf(st[kvb][f * 8 + 0], st[kvb][f * 8 + 1]);
        uint32_t wb = pkbf(st[kvb][f * 8 + 2], st[kvb][f * 8 + 3]);
        uint32_t wc = pkbf(st[kvb][f * 8 + 4], st[kvb][f * 8 + 5]);
        uint32_t wd = pkbf(st[kvb][f * 8 + 6], st[kvb][f * 8 + 7]);
        asm volatile("v_permlane32_swap_b32 %0, %1" : "+v"(wa), "+v"(wc));
        asm volatile("v_permlane32_swap_b32 %0, %1" : "+v"(wb), "+v"(wd));
        union { uint32_t w[4]; short8 v; } u;
        u.w[0] = wa; u.w[1] = wb; u.w[2] = wc; u.w[3] = wd;
        pa[kvb * 2 + f] = u.v;
      }

    // O += P V  (B-operand = V^T rows d)
    #pragma unroll
    for (int db = 0; db < 2; ++db) {
      short8 vb[4];
      #pragma unroll
      for (int k4 = 0; k4 < 4; ++k4) {
        const int row = db * 32 + lo, ch = k4 * 2 + hi;
        vb[k4] = *reinterpret_cast<const short8*>(
            &sVt[cur][(row * 8 + (ch ^ (row & 7))) * 8]);
      }
      acc[db] = mfma32(pa[0], vb[0], acc[db]);
      acc[db] = mfma32(pa[1], vb[1], acc[db]);
      acc[db] = mfma32(pa[2], vb[2], acc[db]);
      acc[db] = mfma32(pa[3], vb[3], acc[db]);
    }
  }

  // epilogue: O /= l, write bf16 [8192][1024]
  sBc[wq][lo] = 1.f / lst;
  lgkm0();
  #pragma unroll
  for (int g = 0; g < 4; ++g) {
    const f32x4 r4 = *reinterpret_cast<const f32x4*>(&sBc[wq][g * 8 + hi * 4]);
    #pragma unroll
    for (int j = 0; j < 4; ++j) {
      const int qrow = q0 + wq * 32 + g * 8 + hi * 4 + j;
      #pragma unroll
      for (int db = 0; db < 2; ++db)
        outp[(size_t)(b * SEQ + qrow) * EMBED + h * 64 + db * 32 + lo] =
            f2bf(acc[db][g * 4 + j] * r4[j]);
    }
  }
}

// ---------------- launch ----------------
extern "C" void kernel_launch(void* const* d_in, const int* in_sizes, int n_in,
                              void* d_out, int out_size, void* d_ws, size_t ws_size,
                              hipStream_t stream) {
  const float* x     = (const float*)d_in[0];
  const float* ln1_g = (const float*)d_in[1];
  const float* ln1_b = (const float*)d_in[2];
  const float* qkv_w = (const float*)d_in[3];
  const float* out_w = (const float*)d_in[4];
  const float* out_b = (const float*)d_in[5];
  const float* ln2_g = (const float*)d_in[6];
  const float* ln2_b = (const float*)d_in[7];
  const float* fc1_w = (const float*)d_in[8];
  const float* fc1_b = (const float*)d_in[9];
  const float* fc2_w = (const float*)d_in[10];
  const float* fc2_b = (const float*)d_in[11];
  float* out = (float*)d_out;
  char* ws = (char*)d_ws;

  // workspace layout (bytes)
  ushort* qkvw = (ushort*)(ws);                                   //  6291456
  ushort* outw = (ushort*)(ws + 6291456);                         //  2097152
  ushort* fc1w = (ushort*)(ws + 8388608);                         //  8388608
  ushort* fc2w = (ushort*)(ws + 16777216);                        //  8388608
  float*  x1   = (float*) (ws + 25165824);                        // 33554432
  ushort* hbuf = (ushort*)(ws + 58720256);                        // 16777216
  ushort* qkbuf= (ushort*)(ws + 75497472);                        // 33554432  [8192][2048]
  ushort* vtbuf= (ushort*)(ws + 109051904);                       // 16777216  [1024][8192]
  ushort* obuf = (ushort*)(ws + 125829120);                       // 16777216
  ushort* gbuf = qkbuf;  // gelu buf [8192][4096] reuses qk+vt+o regions (64 MiB)

  // all four weight conversions in one launch (grid-stride)
  cvt4_kernel<<<2048, 256, 0, stream>>>(qkv_w, qkvw, 3 * EMBED * EMBED / 4,
                                        out_w, outw, EMBED * EMBED / 4,
                                        fc1_w, fc1w, HIDDEN * EMBED / 4,
                                        fc2_w, fc2w, EMBED * HIDDEN / 4);

  ln_kernel<<<NTOK, 256, 0, stream>>>(x, ln1_g, ln1_b, hbuf);
  // QK: [8192][2048] = hbuf * Wqk^T   (EPI 3: Q cols scaled by log2e)
  gemm256<3, true><<<256, 512, 0, stream>>>(hbuf, qkvw, nullptr, nullptr,
                                            qkbuf, nullptr, NTOK, 2 * EMBED, EMBED, 32);
  // V^T: [1024][8192] = Wv * hbuf^T   (256x128 tiles, N-partitioned)
  gemm256<0, false><<<256, 512, 0, stream>>>(qkvw + 2048 * 1024, hbuf, nullptr, nullptr,
                                             vtbuf, nullptr, EMBED, NTOK, EMBED, 4);
  attn_kernel<<<dim3(64, 8), 512, 0, stream>>>(qkbuf, vtbuf, obuf);
  // out-proj
  gemm256<1, false><<<256, 512, 0, stream>>>(obuf, outw, out_b, x,
                                             nullptr, x1, NTOK, EMBED, EMBED, 32);
  ln_kernel<<<NTOK, 256, 0, stream>>>(x1, ln2_g, ln2_b, hbuf);
  // fc1
  gemm256<2, true><<<512, 512, 0, stream>>>(hbuf, fc1w, fc1_b, nullptr,
                                            gbuf, nullptr, NTOK, HIDDEN, EMBED, 32);
  // fc2
  gemm256<1, false><<<256, 512, 0, stream>>>(gbuf, fc2w, fc2_b, x1,
                                             nullptr, out, NTOK, EMBED, HIDDEN, 32);
}

// Round 18
// 378.289 us; speedup vs baseline: 1.0362x; 1.0066x over previous
//
#include <hip/hip_runtime.h>
#include <cstdint>

// Transformer block: LN1 -> {QK GEMM, V^T GEMM} -> flash attn (swapped-QK,
// in-register softmax, permlane P re-layout) -> out-proj(+res) -> LN2
// -> fc1(+GELU) -> fc2(+res). All matmuls bf16 MFMA, fp32 accum.
// R18 = R15/R17 config with ONE barrier per K-tile (mid-tile barriers removed;
// hazard audit: RAW covered by tile-boundary vwait+barrier of tile u-1, WAR
// covered because sbuf's readers finished before tile u-1's end barrier and
// a fast wave can't pass tile u's end barrier early). Ledger unchanged.

using short8 = __attribute__((ext_vector_type(8))) short;
using f32x4  = __attribute__((ext_vector_type(4))) float;
using f32x16 = __attribute__((ext_vector_type(16))) float;

#define EMBED  1024
#define HIDDEN 4096
#define SEQ    2048
#define NTOK   8192   // 4*2048
#define LOG2E  1.4426950408889634f

__device__ __forceinline__ ushort f2bf(float x) {
  union { float f; uint32_t u; } v; v.f = x;
  uint32_t r = v.u + 0x7fffu + ((v.u >> 16) & 1u);   // RNE
  return (ushort)(r >> 16);
}

__device__ __forceinline__ uint32_t pkbf(float lo, float hi) {
  uint32_t r;
  asm("v_cvt_pk_bf16_f32 %0, %1, %2" : "=v"(r) : "v"(lo), "v"(hi));
  return r;
}

__device__ __forceinline__ void gload16(const void* g, void* l) {
  __builtin_amdgcn_global_load_lds((__attribute__((address_space(1))) void*)(g),
                                   (__attribute__((address_space(3))) void*)(l), 16, 0, 0);
}

template<int N> __device__ __forceinline__ void vwait() {
  asm volatile("s_waitcnt vmcnt(%0)" :: "n"(N) : "memory");
}
__device__ __forceinline__ void lgkm0() {
  asm volatile("s_waitcnt lgkmcnt(0)" ::: "memory");
}
__device__ __forceinline__ void fence_bar() {
  asm volatile("" ::: "memory");
  __builtin_amdgcn_s_barrier();
  asm volatile("" ::: "memory");
}

__device__ __forceinline__ f32x4 mfma16(short8 a, short8 b, f32x4 c) {
  return __builtin_amdgcn_mfma_f32_16x16x32_bf16(a, b, c, 0, 0, 0);
}
__device__ __forceinline__ f32x16 mfma32(short8 a, short8 b, f32x16 c) {
  return __builtin_amdgcn_mfma_f32_32x32x16_bf16(a, b, c, 0, 0, 0);
}
__device__ __forceinline__ f32x16 zero16() {
  f32x16 z = {0.f,0.f,0.f,0.f,0.f,0.f,0.f,0.f,0.f,0.f,0.f,0.f,0.f,0.f,0.f,0.f};
  return z;
}

// ---------------- fp32 -> bf16 weight conversion (all 4 weights, 1 launch) ----------------
__global__ __launch_bounds__(256) void cvt4_kernel(const float* __restrict__ s0, ushort* __restrict__ d0, int n0,
                                                   const float* __restrict__ s1, ushort* __restrict__ d1, int n1,
                                                   const float* __restrict__ s2, ushort* __restrict__ d2, int n2,
                                                   const float* __restrict__ s3, ushort* __restrict__ d3, int n3) {
  const int total = n0 + n1 + n2 + n3;
  for (int i = blockIdx.x * 256 + threadIdx.x; i < total; i += gridDim.x * 256) {
    const float* s; ushort* d; int j = i;
    if (j < n0) { s = s0; d = d0; }
    else {
      j -= n0;
      if (j < n1) { s = s1; d = d1; }
      else {
        j -= n1;
        if (j < n2) { s = s2; d = d2; }
        else { j -= n2; s = s3; d = d3; }
      }
    }
    const float4 v = reinterpret_cast<const float4*>(s)[j];
    ushort4 o; o.x = f2bf(v.x); o.y = f2bf(v.y); o.z = f2bf(v.z); o.w = f2bf(v.w);
    reinterpret_cast<ushort4*>(d)[j] = o;
  }
}

// ---------------- LayerNorm (fp32 in, bf16 out) ----------------
__global__ __launch_bounds__(256) void ln_kernel(const float* __restrict__ x,
                                                 const float* __restrict__ g,
                                                 const float* __restrict__ b,
                                                 ushort* __restrict__ out) {
  const int row = blockIdx.x, tid = threadIdx.x;
  const float4 xv = reinterpret_cast<const float4*>(x + (size_t)row * EMBED)[tid];
  float s  = xv.x + xv.y + xv.z + xv.w;
  float s2 = xv.x*xv.x + xv.y*xv.y + xv.z*xv.z + xv.w*xv.w;
  #pragma unroll
  for (int off = 32; off >= 1; off >>= 1) { s += __shfl_xor(s, off); s2 += __shfl_xor(s2, off); }
  __shared__ float ps[4], ps2[4];
  if ((tid & 63) == 0) { ps[tid >> 6] = s; ps2[tid >> 6] = s2; }
  __syncthreads();
  s  = ps[0] + ps[1] + ps[2] + ps[3];
  s2 = ps2[0] + ps2[1] + ps2[2] + ps2[3];
  const float mu  = s * (1.f / EMBED);
  const float var = s2 * (1.f / EMBED) - mu * mu;
  const float rs  = rsqrtf(var + 1e-5f);
  const float4 gv = reinterpret_cast<const float4*>(g)[tid];
  const float4 bv = reinterpret_cast<const float4*>(b)[tid];
  ushort4 o;
  o.x = f2bf((xv.x - mu) * rs * gv.x + bv.x);
  o.y = f2bf((xv.y - mu) * rs * gv.y + bv.y);
  o.z = f2bf((xv.z - mu) * rs * gv.z + bv.z);
  o.w = f2bf((xv.w - mu) * rs * gv.w + bv.w);
  reinterpret_cast<ushort4*>(out + (size_t)row * EMBED)[tid] = o;
}

// ---------------- bf16 GEMM: C[M,N] = A[M,K] * B[N,K]^T (+epilogue) ----------------
// SQ=true: 256x256 tile (8 waves 2Mx4N). SQ=false: 256x128 tile (8 waves 4Mx2N).
// Quad-buffered BK=32 tiles; stage tile u+3 during tile u; counted vmcnt;
// x4 unroll; ONE vwait+barrier per tile (mid-tile barriers removed, see audit).
// L2-locality partition: XCD p owns contiguous M-slice (or N-slice if gx<8).
// EPI: 0 bf16 | 1 fp32+bias+res | 2 bf16 gelu(acc+bias) | 3 bf16, cols<1024 * log2e
template<int EPI, bool SQ>
__global__ __launch_bounds__(512) void gemm256(const ushort* __restrict__ A,
                                               const ushort* __restrict__ B,
                                               const float* __restrict__ bias,
                                               const float* __restrict__ res,
                                               ushort* __restrict__ outb,
                                               float* __restrict__ outf,
                                               int M, int N, int K, int gx) {
  constexpr int BN   = SQ ? 256 : 128;
  constexpr int MP   = SQ ? 8 : 4;          // 16-row m-positions per wave
  constexpr int NPH  = SQ ? 2 : 1;          // phases per K-tile
  constexpr int LPT  = SQ ? 4 : 3;          // gload16 rounds per tile per thread
  constexpr int NB   = LPT - 2;             // B staging rounds
  constexpr int ABUF = 256 * 32;            // ushorts
  constexpr int BBUF = BN * 32;
  __shared__ ushort lds[4][ABUF + BBUF];

  const int nwg = gridDim.x;                // nwg % 8 == 0 for all our shapes
  const int b0  = blockIdx.x;
  // locality partition (XCD = blockIdx % 8)
  const int p = b0 & 7, li = b0 >> 3;
  int mt, nt;
  if ((gx & 7) == 0) {                      // partition M across XCDs
    const int g = gx >> 3;                  // m-tiles per XCD
    mt = p * g + (li % g);                  // m fastest within XCD
    nt = li / g;
  } else {                                  // partition N across XCDs (gy%8==0)
    const int g = (nwg / gx) >> 3;          // n-tiles per XCD
    nt = p * g + (li % g);                  // n fastest within XCD
    mt = li / g;
  }
  const int m0 = mt * 256;
  const int n0 = nt * BN;

  const int tid = threadIdx.x, lane = tid & 63, wave = tid >> 6;
  const int wm = (SQ ? (wave >> 2) : (wave >> 1)) * (MP * 16);
  const int wn = (SQ ? (wave & 3) : (wave & 1)) * 64;
  const int l15 = lane & 15, l4 = lane >> 4;
  const int NT = K >> 5;                    // divisible by 4 for all our shapes

  // per-thread staging source pointers; advance +32 elems per staged tile
  const ushort* aSrc[2];
  const ushort* bSrc[NB];
  #pragma unroll
  for (int rd = 0; rd < 2; ++rd) {
    const int slot = rd * 512 + tid;
    const int r = slot >> 2;
    const int cs = (slot & 3) ^ ((r >> 1) & 3);
    aSrc[rd] = A + (size_t)(m0 + r) * K + cs * 8;
  }
  #pragma unroll
  for (int rd = 0; rd < NB; ++rd) {
    const int slot = rd * 512 + tid;
    const int r = slot >> 2;
    const int cs = (slot & 3) ^ ((r >> 1) & 3);
    bSrc[rd] = B + (size_t)(n0 + r) * K + cs * 8;
  }
  auto stageA = [&](int buf, int rd) { gload16(aSrc[rd], &lds[buf][(rd * 512 + tid) * 8]); };
  auto stageB = [&](int buf, int rd) { gload16(bSrc[rd], &lds[buf][ABUF + (rd * 512 + tid) * 8]); };
  auto advance = [&]() {
    #pragma unroll
    for (int rd = 0; rd < 2; ++rd) aSrc[rd] += 32;
    #pragma unroll
    for (int rd = 0; rd < NB; ++rd) bSrc[rd] += 32;
  };

  // prologue: stage tiles 0..2 into bufs 0..2
  #pragma unroll
  for (int t = 0; t < 3; ++t) {
    stageA(t, 0); stageA(t, 1);
    #pragma unroll
    for (int rd = 0; rd < NB; ++rd) stageB(t, rd);
    advance();
  }
  vwait<2 * LPT>();               // tile 0 resident; 2 tiles stay in flight
  fence_bar();

  f32x4 acc[MP][4] = {};

  // one K-tile; q = buffer index (compile-time at every call site),
  // st = stage tile u+3, wsel: 0 -> vwait(2LPT), 1 -> vwait(LPT), 2 -> vwait(0), 3 -> none
  // Single sync point per tile: vwait + barrier at the tile boundary.
  auto doTile = [&](int q, bool st, int wsel) {
    const ushort* bA = &lds[q][0];
    const ushort* bB = &lds[q][ABUF];
    const int sbuf = (q + 3) & 3;
    short8 bf[4];
    #pragma unroll
    for (int j = 0; j < 4; ++j) {
      const int rb = wn + j * 16 + l15;
      bf[j] = *reinterpret_cast<const short8*>(&bB[rb * 32 + ((l4 ^ ((rb >> 1) & 3)) * 8)]);
    }
    #pragma unroll
    for (int ph = 0; ph < NPH; ++ph) {
      short8 af[4];
      #pragma unroll
      for (int i = 0; i < 4; ++i) {
        const int ra = wm + (ph * 4 + i) * 16 + l15;
        af[i] = *reinterpret_cast<const short8*>(&bA[ra * 32 + ((l4 ^ ((ra >> 1) & 3)) * 8)]);
      }
      if (st) {
        if constexpr (SQ) {
          if (ph == 0) { stageA(sbuf, 0); stageA(sbuf, 1); }
          else         { stageB(sbuf, 0); stageB(sbuf, 1); }
        } else {
          stageA(sbuf, 0); stageA(sbuf, 1); stageB(sbuf, 0);
        }
      }
      __builtin_amdgcn_s_setprio(1);
      #pragma unroll
      for (int i = 0; i < 4; ++i)
        #pragma unroll
        for (int j = 0; j < 4; ++j)
          acc[ph * 4 + i][j] = mfma16(af[i], bf[j], acc[ph * 4 + i][j]);
      __builtin_amdgcn_s_setprio(0);
    }
    if (st) advance();
    if (wsel == 0)      vwait<2 * LPT>();   // next tile's data resident
    else if (wsel == 1) vwait<LPT>();
    else if (wsel == 2) vwait<0>();
    fence_bar();
  };

  for (int u0 = 0; u0 < NT - 4; u0 += 4) {
    doTile(0, true, 0); doTile(1, true, 0); doTile(2, true, 0); doTile(3, true, 0);
  }
  // tail: u = NT-4 .. NT-1
  doTile(0, true, 0); doTile(1, false, 1); doTile(2, false, 2); doTile(3, false, 3);

  #pragma unroll
  for (int i = 0; i < MP; ++i)
    #pragma unroll
    for (int j = 0; j < 4; ++j)
      #pragma unroll
      for (int r = 0; r < 4; ++r) {
        const int row = m0 + wm + i * 16 + l4 * 4 + r;
        const int col = n0 + wn + j * 16 + l15;
        const size_t idx = (size_t)row * N + col;
        float v = acc[i][j][r];
        if constexpr (EPI == 0) {
          outb[idx] = f2bf(v);
        } else if constexpr (EPI == 1) {
          outf[idx] = v + bias[col] + res[idx];
        } else if constexpr (EPI == 2) {
          v += bias[col];
          v = 0.5f * v * (1.f + erff(v * 0.70710678118654752f));
          outb[idx] = f2bf(v);
        } else {
          // EPI 3: scale Q columns (col < 1024) by log2e for exp2-domain softmax
          outb[idx] = f2bf((col < 1024) ? v * LOG2E : v);
        }
      }
}

// ---------------- flash attention, swapped-QK, exp2-domain softmax ----------------
// grid (B*H=64, SEQ/256=8), block 512 (8 waves). Wave: 32 q rows.
// qk: [8192][2048] bf16 (q*log2e at col h*64, k at col 1024+h*64).
// vt: [1024][8192] bf16. S' = S*log2e -> P = exp2(S'-m') via raw v_exp_f32.
// No 1/sqrt(d) scaling (per reference). 16 waves/CU.
#define KVB 64
#define NTT (SEQ / KVB)

__global__ __launch_bounds__(512, 4) void attn_kernel(const ushort* __restrict__ qk,
                                                      const ushort* __restrict__ vt,
                                                      ushort* __restrict__ outp) {
  const int tid = threadIdx.x, lane = tid & 63, wq = tid >> 6;   // wq 0..7
  const int hi = lane >> 5, lo = lane & 31;
  const int b = blockIdx.x >> 4, h = blockIdx.x & 15;
  const int q0 = blockIdx.y * 256;

  __shared__ ushort sK[2][64 * 64];
  __shared__ ushort sVt[2][64 * 64];
  __shared__ float sBc[8][32];

  // Q fragments (B-operand): wave covers q rows q0 + wq*32 .. +31 (lane q = lo)
  short8 qf[4];
  #pragma unroll
  for (int kc = 0; kc < 4; ++kc)
    qf[kc] = *reinterpret_cast<const short8*>(
        qk + (size_t)(b * SEQ + q0 + wq * 32 + lo) * 2048 + h * 64 + kc * 16 + hi * 8);

  auto STAGE = [&](int bb, int kt) {
    const int r = tid >> 3;
    const int c = (tid & 7) ^ (r & 7);            // inverse-swizzled source chunk
    gload16(qk + (size_t)(b * SEQ + kt + r) * 2048 + 1024 + h * 64 + c * 8,
            &sK[bb][wq * 64 * 8]);                // wave-uniform dest + lane*16B
    gload16(vt + (size_t)(h * 64 + r) * 8192 + b * SEQ + kt + c * 8,
            &sVt[bb][wq * 64 * 8]);
  };

  f32x16 acc[2];
  acc[0] = zero16(); acc[1] = zero16();
  float mst = -1e30f, lst = 0.f;

  STAGE(0, 0);
  for (int t = 0; t < NTT; ++t) {
    const int cur = t & 1;
    __syncthreads();                       // staged buf[cur] ready; buf[cur^1] free
    if (t + 1 < NTT) STAGE(cur ^ 1, (t + 1) * KVB);

    // K fragments (A-operand): row kv, swizzled b128 reads
    short8 kf[2][4];
    #pragma unroll
    for (int kvb = 0; kvb < 2; ++kvb)
      #pragma unroll
      for (int kc = 0; kc < 4; ++kc) {
        const int row = kvb * 32 + lo, ch = kc * 2 + hi;
        kf[kvb][kc] = *reinterpret_cast<const short8*>(
            &sK[cur][(row * 8 + (ch ^ (row & 7))) * 8]);
      }

    // S'^T = K * (Q*log2e)^T : lane holds q=lo, kv rows in regs (exp2 domain)
    f32x16 st[2];
    #pragma unroll
    for (int kvb = 0; kvb < 2; ++kvb) {
      f32x16 tq = zero16();
      tq = mfma32(kf[kvb][0], qf[0], tq);
      tq = mfma32(kf[kvb][1], qf[1], tq);
      tq = mfma32(kf[kvb][2], qf[2], tq);
      tq = mfma32(kf[kvb][3], qf[3], tq);
      st[kvb] = tq;
    }
    // row max: pairwise combine + max3-fusable triple chain
    f32x16 mm;
    #pragma unroll
    for (int r = 0; r < 16; ++r) mm[r] = fmaxf(st[0][r], st[1][r]);
    float pm = fmaxf(fmaxf(mm[0], mm[1]), mm[2]);
    pm = fmaxf(fmaxf(pm, mm[3]), mm[4]);
    pm = fmaxf(fmaxf(pm, mm[5]), mm[6]);
    pm = fmaxf(fmaxf(pm, mm[7]), mm[8]);
    pm = fmaxf(fmaxf(pm, mm[9]), mm[10]);
    pm = fmaxf(fmaxf(pm, mm[11]), mm[12]);
    pm = fmaxf(fmaxf(pm, mm[13]), mm[14]);
    pm = fmaxf(pm, mm[15]);
    pm = fmaxf(pm, __shfl_xor(pm, 32));
    // defer-max (exp2 domain): 8 nats = 11.54 bits
    if (__any(pm > mst + 11.54f)) {
      const float mn = fmaxf(mst, pm);
      const float al = __builtin_amdgcn_exp2f(mst - mn);
      mst = mn; lst *= al;
      sBc[wq][lo] = al;
      lgkm0();
      #pragma unroll
      for (int g = 0; g < 4; ++g) {
        const f32x4 a4 = *reinterpret_cast<const f32x4*>(&sBc[wq][g * 8 + hi * 4]);
        #pragma unroll
        for (int j = 0; j < 4; ++j) {
          acc[0][g * 4 + j] *= a4[j];
          acc[1][g * 4 + j] *= a4[j];
        }
      }
    }
    // P = exp2(S' - m'), row sum  (raw v_exp_f32, no libcall, no pre-mul)
    #pragma unroll
    for (int kvb = 0; kvb < 2; ++kvb)
      #pragma unroll
      for (int r = 0; r < 16; ++r)
        st[kvb][r] = __builtin_amdgcn_exp2f(st[kvb][r] - mst);
    {
      const f32x16 sv = st[0] + st[1];
      float sum = ((sv[0] + sv[1]) + (sv[2] + sv[3])) + ((sv[4] + sv[5]) + (sv[6] + sv[7]))
                + ((sv[8] + sv[9]) + (sv[10] + sv[11])) + ((sv[12] + sv[13]) + (sv[14] + sv[15]));
      sum += __shfl_xor(sum, 32);
      lst += sum;
    }
    // pack P -> bf16 A-fragments via cvt_pk + permlane32_swap
    short8 pa[4];
    #pragma unroll
    for (int kvb = 0; kvb < 2; ++kvb)
      #pragma unroll
      for (int f = 0; f < 2; ++f) {
        uint32_t wa = pkbf(st[kvb][f * 8 + 0], st[kvb][f * 8 + 1]);
        uint32_t wb = pkbf(st[kvb][f * 8 + 2], st[kvb][f * 8 + 3]);
        uint32_t wc = pkbf(st[kvb][f * 8 + 4], st[kvb][f * 8 + 5]);
        uint32_t wd = pkbf(st[kvb][f * 8 + 6], st[kvb][f * 8 + 7]);
        asm volatile("v_permlane32_swap_b32 %0, %1" : "+v"(wa), "+v"(wc));
        asm volatile("v_permlane32_swap_b32 %0, %1" : "+v"(wb), "+v"(wd));
        union { uint32_t w[4]; short8 v; } u;
        u.w[0] = wa; u.w[1] = wb; u.w[2] = wc; u.w[3] = wd;
        pa[kvb * 2 + f] = u.v;
      }

    // O += P V  (B-operand = V^T rows d)
    #pragma unroll
    for (int db = 0; db < 2; ++db) {
      short8 vb[4];
      #pragma unroll
      for (int k4 = 0; k4 < 4; ++k4) {
        const int row = db * 32 + lo, ch = k4 * 2 + hi;
        vb[k4] = *reinterpret_cast<const short8*>(
            &sVt[cur][(row * 8 + (ch ^ (row & 7))) * 8]);
      }
      acc[db] = mfma32(pa[0], vb[0], acc[db]);
      acc[db] = mfma32(pa[1], vb[1], acc[db]);
      acc[db] = mfma32(pa[2], vb[2], acc[db]);
      acc[db] = mfma32(pa[3], vb[3], acc[db]);
    }
  }

  // epilogue: O /= l, write bf16 [8192][1024]
  sBc[wq][lo] = 1.f / lst;
  lgkm0();
  #pragma unroll
  for (int g = 0; g < 4; ++g) {
    const f32x4 r4 = *reinterpret_cast<const f32x4*>(&sBc[wq][g * 8 + hi * 4]);
    #pragma unroll
    for (int j = 0; j < 4; ++j) {
      const int qrow = q0 + wq * 32 + g * 8 + hi * 4 + j;
      #pragma unroll
      for (int db = 0; db < 2; ++db)
        outp[(size_t)(b * SEQ + qrow) * EMBED + h * 64 + db * 32 + lo] =
            f2bf(acc[db][g * 4 + j] * r4[j]);
    }
  }
}

// ---------------- launch ----------------
extern "C" void kernel_launch(void* const* d_in, const int* in_sizes, int n_in,
                              void* d_out, int out_size, void* d_ws, size_t ws_size,
                              hipStream_t stream) {
  const float* x     = (const float*)d_in[0];
  const float* ln1_g = (const float*)d_in[1];
  const float* ln1_b = (const float*)d_in[2];
  const float* qkv_w = (const float*)d_in[3];
  const float* out_w = (const float*)d_in[4];
  const float* out_b = (const float*)d_in[5];
  const float* ln2_g = (const float*)d_in[6];
  const float* ln2_b = (const float*)d_in[7];
  const float* fc1_w = (const float*)d_in[8];
  const float* fc1_b = (const float*)d_in[9];
  const float* fc2_w = (const float*)d_in[10];
  const float* fc2_b = (const float*)d_in[11];
  float* out = (float*)d_out;
  char* ws = (char*)d_ws;

  // workspace layout (bytes)
  ushort* qkvw = (ushort*)(ws);                                   //  6291456
  ushort* outw = (ushort*)(ws + 6291456);                         //  2097152
  ushort* fc1w = (ushort*)(ws + 8388608);                         //  8388608
  ushort* fc2w = (ushort*)(ws + 16777216);                        //  8388608
  float*  x1   = (float*) (ws + 25165824);                        // 33554432
  ushort* hbuf = (ushort*)(ws + 58720256);                        // 16777216
  ushort* qkbuf= (ushort*)(ws + 75497472);                        // 33554432  [8192][2048]
  ushort* vtbuf= (ushort*)(ws + 109051904);                       // 16777216  [1024][8192]
  ushort* obuf = (ushort*)(ws + 125829120);                       // 16777216
  ushort* gbuf = qkbuf;  // gelu buf [8192][4096] reuses qk+vt+o regions (64 MiB)

  // all four weight conversions in one launch (grid-stride)
  cvt4_kernel<<<2048, 256, 0, stream>>>(qkv_w, qkvw, 3 * EMBED * EMBED / 4,
                                        out_w, outw, EMBED * EMBED / 4,
                                        fc1_w, fc1w, HIDDEN * EMBED / 4,
                                        fc2_w, fc2w, EMBED * HIDDEN / 4);

  ln_kernel<<<NTOK, 256, 0, stream>>>(x, ln1_g, ln1_b, hbuf);
  // QK: [8192][2048] = hbuf * Wqk^T   (EPI 3: Q cols scaled by log2e)
  gemm256<3, true><<<256, 512, 0, stream>>>(hbuf, qkvw, nullptr, nullptr,
                                            qkbuf, nullptr, NTOK, 2 * EMBED, EMBED, 32);
  // V^T: [1024][8192] = Wv * hbuf^T   (256x128 tiles, N-partitioned)
  gemm256<0, false><<<256, 512, 0, stream>>>(qkvw + 2048 * 1024, hbuf, nullptr, nullptr,
                                             vtbuf, nullptr, EMBED, NTOK, EMBED, 4);
  attn_kernel<<<dim3(64, 8), 512, 0, stream>>>(qkbuf, vtbuf, obuf);
  // out-proj
  gemm256<1, false><<<256, 512, 0, stream>>>(obuf, outw, out_b, x,
                                             nullptr, x1, NTOK, EMBED, EMBED, 32);
  ln_kernel<<<NTOK, 256, 0, stream>>>(x1, ln2_g, ln2_b, hbuf);
  // fc1
  gemm256<2, true><<<512, 512, 0, stream>>>(hbuf, fc1w, fc1_b, nullptr,
                                            gbuf, nullptr, NTOK, HIDDEN, EMBED, 32);
  // fc2
  gemm256<1, false><<<256, 512, 0, stream>>>(gbuf, fc2w, fc2_b, x1,
                                             nullptr, out, NTOK, EMBED, HIDDEN, 32);
}

// Round 19
// 375.566 us; speedup vs baseline: 1.0437x; 1.0073x over previous
//
#include <hip/hip_runtime.h>
#include <cstdint>

// Transformer block: LN1 -> {QK GEMM, V^T GEMM} -> flash attn (swapped-QK,
// in-register softmax exp2-domain, permlane P re-layout) -> out-proj(+res)
// -> LN2 -> fc1(+GELU) -> fc2(+res). All matmuls bf16 MFMA, fp32 accum.
// R19 = R18 (best: 378.3 us; quad-buffer 1-barrier/tile gemm256 + locality,
// 8-wave exp2 attn) + cvt4/LN1 fused into one dispatch (independent work,
// disjoint block ranges -> memory-bound overlap).

using short8 = __attribute__((ext_vector_type(8))) short;
using f32x4  = __attribute__((ext_vector_type(4))) float;
using f32x16 = __attribute__((ext_vector_type(16))) float;

#define EMBED  1024
#define HIDDEN 4096
#define SEQ    2048
#define NTOK   8192   // 4*2048
#define LOG2E  1.4426950408889634f

__device__ __forceinline__ ushort f2bf(float x) {
  union { float f; uint32_t u; } v; v.f = x;
  uint32_t r = v.u + 0x7fffu + ((v.u >> 16) & 1u);   // RNE
  return (ushort)(r >> 16);
}

__device__ __forceinline__ uint32_t pkbf(float lo, float hi) {
  uint32_t r;
  asm("v_cvt_pk_bf16_f32 %0, %1, %2" : "=v"(r) : "v"(lo), "v"(hi));
  return r;
}

__device__ __forceinline__ void gload16(const void* g, void* l) {
  __builtin_amdgcn_global_load_lds((__attribute__((address_space(1))) void*)(g),
                                   (__attribute__((address_space(3))) void*)(l), 16, 0, 0);
}

template<int N> __device__ __forceinline__ void vwait() {
  asm volatile("s_waitcnt vmcnt(%0)" :: "n"(N) : "memory");
}
__device__ __forceinline__ void lgkm0() {
  asm volatile("s_waitcnt lgkmcnt(0)" ::: "memory");
}
__device__ __forceinline__ void fence_bar() {
  asm volatile("" ::: "memory");
  __builtin_amdgcn_s_barrier();
  asm volatile("" ::: "memory");
}

__device__ __forceinline__ f32x4 mfma16(short8 a, short8 b, f32x4 c) {
  return __builtin_amdgcn_mfma_f32_16x16x32_bf16(a, b, c, 0, 0, 0);
}
__device__ __forceinline__ f32x16 mfma32(short8 a, short8 b, f32x16 c) {
  return __builtin_amdgcn_mfma_f32_32x32x16_bf16(a, b, c, 0, 0, 0);
}
__device__ __forceinline__ f32x16 zero16() {
  f32x16 z = {0.f,0.f,0.f,0.f,0.f,0.f,0.f,0.f,0.f,0.f,0.f,0.f,0.f,0.f,0.f,0.f};
  return z;
}

// ---------------- LN row body (shared by fused kernel and ln2) ----------------
__device__ __forceinline__ void ln_row(const float* __restrict__ x,
                                       const float* __restrict__ g,
                                       const float* __restrict__ b,
                                       ushort* __restrict__ out, int row, int tid) {
  const float4 xv = reinterpret_cast<const float4*>(x + (size_t)row * EMBED)[tid];
  float s  = xv.x + xv.y + xv.z + xv.w;
  float s2 = xv.x*xv.x + xv.y*xv.y + xv.z*xv.z + xv.w*xv.w;
  #pragma unroll
  for (int off = 32; off >= 1; off >>= 1) { s += __shfl_xor(s, off); s2 += __shfl_xor(s2, off); }
  __shared__ float ps[4], ps2[4];
  if ((tid & 63) == 0) { ps[tid >> 6] = s; ps2[tid >> 6] = s2; }
  __syncthreads();
  s  = ps[0] + ps[1] + ps[2] + ps[3];
  s2 = ps2[0] + ps2[1] + ps2[2] + ps2[3];
  const float mu  = s * (1.f / EMBED);
  const float var = s2 * (1.f / EMBED) - mu * mu;
  const float rs  = rsqrtf(var + 1e-5f);
  const float4 gv = reinterpret_cast<const float4*>(g)[tid];
  const float4 bv = reinterpret_cast<const float4*>(b)[tid];
  ushort4 o;
  o.x = f2bf((xv.x - mu) * rs * gv.x + bv.x);
  o.y = f2bf((xv.y - mu) * rs * gv.y + bv.y);
  o.z = f2bf((xv.z - mu) * rs * gv.z + bv.z);
  o.w = f2bf((xv.w - mu) * rs * gv.w + bv.w);
  reinterpret_cast<ushort4*>(out + (size_t)row * EMBED)[tid] = o;
}

// ---------------- fused: LN1 (blocks 0..8191) + weight cvt (blocks 8192..10239) ----------------
__global__ __launch_bounds__(256) void ln_cvt_kernel(const float* __restrict__ x,
                                                     const float* __restrict__ ln_g,
                                                     const float* __restrict__ ln_b,
                                                     ushort* __restrict__ hout,
                                                     const float* __restrict__ s0, ushort* __restrict__ d0, int n0,
                                                     const float* __restrict__ s1, ushort* __restrict__ d1, int n1,
                                                     const float* __restrict__ s2, ushort* __restrict__ d2, int n2,
                                                     const float* __restrict__ s3, ushort* __restrict__ d3, int n3) {
  const int tid = threadIdx.x;
  if (blockIdx.x < NTOK) {
    ln_row(x, ln_g, ln_b, hout, blockIdx.x, tid);
    return;
  }
  const int cb = blockIdx.x - NTOK;               // 0..2047
  const int total = n0 + n1 + n2 + n3;
  for (int i = cb * 256 + tid; i < total; i += 2048 * 256) {
    const float* s; ushort* d; int j = i;
    if (j < n0) { s = s0; d = d0; }
    else {
      j -= n0;
      if (j < n1) { s = s1; d = d1; }
      else {
        j -= n1;
        if (j < n2) { s = s2; d = d2; }
        else { j -= n2; s = s3; d = d3; }
      }
    }
    const float4 v = reinterpret_cast<const float4*>(s)[j];
    ushort4 o; o.x = f2bf(v.x); o.y = f2bf(v.y); o.z = f2bf(v.z); o.w = f2bf(v.w);
    reinterpret_cast<ushort4*>(d)[j] = o;
  }
}

// ---------------- LayerNorm (standalone, for LN2) ----------------
__global__ __launch_bounds__(256) void ln_kernel(const float* __restrict__ x,
                                                 const float* __restrict__ g,
                                                 const float* __restrict__ b,
                                                 ushort* __restrict__ out) {
  ln_row(x, g, b, out, blockIdx.x, threadIdx.x);
}

// ---------------- bf16 GEMM: C[M,N] = A[M,K] * B[N,K]^T (+epilogue) ----------------
// SQ=true: 256x256 tile (8 waves 2Mx4N). SQ=false: 256x128 tile (8 waves 4Mx2N).
// Quad-buffered BK=32 tiles; stage tile u+3 during tile u; counted vmcnt;
// x4 unroll; ONE vwait+barrier per tile. L2-locality XCD partition.
// EPI: 0 bf16 | 1 fp32+bias+res | 2 bf16 gelu(acc+bias) | 3 bf16, cols<1024 * log2e
template<int EPI, bool SQ>
__global__ __launch_bounds__(512) void gemm256(const ushort* __restrict__ A,
                                               const ushort* __restrict__ B,
                                               const float* __restrict__ bias,
                                               const float* __restrict__ res,
                                               ushort* __restrict__ outb,
                                               float* __restrict__ outf,
                                               int M, int N, int K, int gx) {
  constexpr int BN   = SQ ? 256 : 128;
  constexpr int MP   = SQ ? 8 : 4;          // 16-row m-positions per wave
  constexpr int NPH  = SQ ? 2 : 1;          // phases per K-tile
  constexpr int LPT  = SQ ? 4 : 3;          // gload16 rounds per tile per thread
  constexpr int NB   = LPT - 2;             // B staging rounds
  constexpr int ABUF = 256 * 32;            // ushorts
  constexpr int BBUF = BN * 32;
  __shared__ ushort lds[4][ABUF + BBUF];

  const int nwg = gridDim.x;                // nwg % 8 == 0 for all our shapes
  const int b0  = blockIdx.x;
  // locality partition (XCD = blockIdx % 8)
  const int p = b0 & 7, li = b0 >> 3;
  int mt, nt;
  if ((gx & 7) == 0) {                      // partition M across XCDs
    const int g = gx >> 3;                  // m-tiles per XCD
    mt = p * g + (li % g);                  // m fastest within XCD
    nt = li / g;
  } else {                                  // partition N across XCDs (gy%8==0)
    const int g = (nwg / gx) >> 3;          // n-tiles per XCD
    nt = p * g + (li % g);                  // n fastest within XCD
    mt = li / g;
  }
  const int m0 = mt * 256;
  const int n0 = nt * BN;

  const int tid = threadIdx.x, lane = tid & 63, wave = tid >> 6;
  const int wm = (SQ ? (wave >> 2) : (wave >> 1)) * (MP * 16);
  const int wn = (SQ ? (wave & 3) : (wave & 1)) * 64;
  const int l15 = lane & 15, l4 = lane >> 4;
  const int NT = K >> 5;                    // divisible by 4 for all our shapes

  // per-thread staging source pointers; advance +32 elems per staged tile
  const ushort* aSrc[2];
  const ushort* bSrc[NB];
  #pragma unroll
  for (int rd = 0; rd < 2; ++rd) {
    const int slot = rd * 512 + tid;
    const int r = slot >> 2;
    const int cs = (slot & 3) ^ ((r >> 1) & 3);
    aSrc[rd] = A + (size_t)(m0 + r) * K + cs * 8;
  }
  #pragma unroll
  for (int rd = 0; rd < NB; ++rd) {
    const int slot = rd * 512 + tid;
    const int r = slot >> 2;
    const int cs = (slot & 3) ^ ((r >> 1) & 3);
    bSrc[rd] = B + (size_t)(n0 + r) * K + cs * 8;
  }
  auto stageA = [&](int buf, int rd) { gload16(aSrc[rd], &lds[buf][(rd * 512 + tid) * 8]); };
  auto stageB = [&](int buf, int rd) { gload16(bSrc[rd], &lds[buf][ABUF + (rd * 512 + tid) * 8]); };
  auto advance = [&]() {
    #pragma unroll
    for (int rd = 0; rd < 2; ++rd) aSrc[rd] += 32;
    #pragma unroll
    for (int rd = 0; rd < NB; ++rd) bSrc[rd] += 32;
  };

  // prologue: stage tiles 0..2 into bufs 0..2
  #pragma unroll
  for (int t = 0; t < 3; ++t) {
    stageA(t, 0); stageA(t, 1);
    #pragma unroll
    for (int rd = 0; rd < NB; ++rd) stageB(t, rd);
    advance();
  }
  vwait<2 * LPT>();               // tile 0 resident; 2 tiles stay in flight
  fence_bar();

  f32x4 acc[MP][4] = {};

  // one K-tile; q = buffer index (compile-time at every call site),
  // st = stage tile u+3, wsel: 0 -> vwait(2LPT), 1 -> vwait(LPT), 2 -> vwait(0), 3 -> none
  // Single sync point per tile: vwait + barrier at the tile boundary.
  auto doTile = [&](int q, bool st, int wsel) {
    const ushort* bA = &lds[q][0];
    const ushort* bB = &lds[q][ABUF];
    const int sbuf = (q + 3) & 3;
    short8 bf[4];
    #pragma unroll
    for (int j = 0; j < 4; ++j) {
      const int rb = wn + j * 16 + l15;
      bf[j] = *reinterpret_cast<const short8*>(&bB[rb * 32 + ((l4 ^ ((rb >> 1) & 3)) * 8)]);
    }
    #pragma unroll
    for (int ph = 0; ph < NPH; ++ph) {
      short8 af[4];
      #pragma unroll
      for (int i = 0; i < 4; ++i) {
        const int ra = wm + (ph * 4 + i) * 16 + l15;
        af[i] = *reinterpret_cast<const short8*>(&bA[ra * 32 + ((l4 ^ ((ra >> 1) & 3)) * 8)]);
      }
      if (st) {
        if constexpr (SQ) {
          if (ph == 0) { stageA(sbuf, 0); stageA(sbuf, 1); }
          else         { stageB(sbuf, 0); stageB(sbuf, 1); }
        } else {
          stageA(sbuf, 0); stageA(sbuf, 1); stageB(sbuf, 0);
        }
      }
      __builtin_amdgcn_s_setprio(1);
      #pragma unroll
      for (int i = 0; i < 4; ++i)
        #pragma unroll
        for (int j = 0; j < 4; ++j)
          acc[ph * 4 + i][j] = mfma16(af[i], bf[j], acc[ph * 4 + i][j]);
      __builtin_amdgcn_s_setprio(0);
    }
    if (st) advance();
    if (wsel == 0)      vwait<2 * LPT>();   // next tile's data resident
    else if (wsel == 1) vwait<LPT>();
    else if (wsel == 2) vwait<0>();
    fence_bar();
  };

  for (int u0 = 0; u0 < NT - 4; u0 += 4) {
    doTile(0, true, 0); doTile(1, true, 0); doTile(2, true, 0); doTile(3, true, 0);
  }
  // tail: u = NT-4 .. NT-1
  doTile(0, true, 0); doTile(1, false, 1); doTile(2, false, 2); doTile(3, false, 3);

  #pragma unroll
  for (int i = 0; i < MP; ++i)
    #pragma unroll
    for (int j = 0; j < 4; ++j)
      #pragma unroll
      for (int r = 0; r < 4; ++r) {
        const int row = m0 + wm + i * 16 + l4 * 4 + r;
        const int col = n0 + wn + j * 16 + l15;
        const size_t idx = (size_t)row * N + col;
        float v = acc[i][j][r];
        if constexpr (EPI == 0) {
          outb[idx] = f2bf(v);
        } else if constexpr (EPI == 1) {
          outf[idx] = v + bias[col] + res[idx];
        } else if constexpr (EPI == 2) {
          v += bias[col];
          v = 0.5f * v * (1.f + erff(v * 0.70710678118654752f));
          outb[idx] = f2bf(v);
        } else {
          // EPI 3: scale Q columns (col < 1024) by log2e for exp2-domain softmax
          outb[idx] = f2bf((col < 1024) ? v * LOG2E : v);
        }
      }
}

// ---------------- flash attention, swapped-QK, exp2-domain softmax ----------------
// grid (B*H=64, SEQ/256=8), block 512 (8 waves). Wave: 32 q rows.
// qk: [8192][2048] bf16 (q*log2e at col h*64, k at col 1024+h*64).
// vt: [1024][8192] bf16. S' = S*log2e -> P = exp2(S'-m') via raw v_exp_f32.
// No 1/sqrt(d) scaling (per reference). 16 waves/CU.
#define KVB 64
#define NTT (SEQ / KVB)

__global__ __launch_bounds__(512, 4) void attn_kernel(const ushort* __restrict__ qk,
                                                      const ushort* __restrict__ vt,
                                                      ushort* __restrict__ outp) {
  const int tid = threadIdx.x, lane = tid & 63, wq = tid >> 6;   // wq 0..7
  const int hi = lane >> 5, lo = lane & 31;
  const int b = blockIdx.x >> 4, h = blockIdx.x & 15;
  const int q0 = blockIdx.y * 256;

  __shared__ ushort sK[2][64 * 64];
  __shared__ ushort sVt[2][64 * 64];
  __shared__ float sBc[8][32];

  // Q fragments (B-operand): wave covers q rows q0 + wq*32 .. +31 (lane q = lo)
  short8 qf[4];
  #pragma unroll
  for (int kc = 0; kc < 4; ++kc)
    qf[kc] = *reinterpret_cast<const short8*>(
        qk + (size_t)(b * SEQ + q0 + wq * 32 + lo) * 2048 + h * 64 + kc * 16 + hi * 8);

  auto STAGE = [&](int bb, int kt) {
    const int r = tid >> 3;
    const int c = (tid & 7) ^ (r & 7);            // inverse-swizzled source chunk
    gload16(qk + (size_t)(b * SEQ + kt + r) * 2048 + 1024 + h * 64 + c * 8,
            &sK[bb][wq * 64 * 8]);                // wave-uniform dest + lane*16B
    gload16(vt + (size_t)(h * 64 + r) * 8192 + b * SEQ + kt + c * 8,
            &sVt[bb][wq * 64 * 8]);
  };

  f32x16 acc[2];
  acc[0] = zero16(); acc[1] = zero16();
  float mst = -1e30f, lst = 0.f;

  STAGE(0, 0);
  for (int t = 0; t < NTT; ++t) {
    const int cur = t & 1;
    __syncthreads();                       // staged buf[cur] ready; buf[cur^1] free
    if (t + 1 < NTT) STAGE(cur ^ 1, (t + 1) * KVB);

    // K fragments (A-operand): row kv, swizzled b128 reads
    short8 kf[2][4];
    #pragma unroll
    for (int kvb = 0; kvb < 2; ++kvb)
      #pragma unroll
      for (int kc = 0; kc < 4; ++kc) {
        const int row = kvb * 32 + lo, ch = kc * 2 + hi;
        kf[kvb][kc] = *reinterpret_cast<const short8*>(
            &sK[cur][(row * 8 + (ch ^ (row & 7))) * 8]);
      }

    // S'^T = K * (Q*log2e)^T : lane holds q=lo, kv rows in regs (exp2 domain)
    f32x16 st[2];
    #pragma unroll
    for (int kvb = 0; kvb < 2; ++kvb) {
      f32x16 tq = zero16();
      tq = mfma32(kf[kvb][0], qf[0], tq);
      tq = mfma32(kf[kvb][1], qf[1], tq);
      tq = mfma32(kf[kvb][2], qf[2], tq);
      tq = mfma32(kf[kvb][3], qf[3], tq);
      st[kvb] = tq;
    }
    // row max: pairwise combine + max3-fusable triple chain
    f32x16 mm;
    #pragma unroll
    for (int r = 0; r < 16; ++r) mm[r] = fmaxf(st[0][r], st[1][r]);
    float pm = fmaxf(fmaxf(mm[0], mm[1]), mm[2]);
    pm = fmaxf(fmaxf(pm, mm[3]), mm[4]);
    pm = fmaxf(fmaxf(pm, mm[5]), mm[6]);
    pm = fmaxf(fmaxf(pm, mm[7]), mm[8]);
    pm = fmaxf(fmaxf(pm, mm[9]), mm[10]);
    pm = fmaxf(fmaxf(pm, mm[11]), mm[12]);
    pm = fmaxf(fmaxf(pm, mm[13]), mm[14]);
    pm = fmaxf(pm, mm[15]);
    pm = fmaxf(pm, __shfl_xor(pm, 32));
    // defer-max (exp2 domain): 8 nats = 11.54 bits
    if (__any(pm > mst + 11.54f)) {
      const float mn = fmaxf(mst, pm);
      const float al = __builtin_amdgcn_exp2f(mst - mn);
      mst = mn; lst *= al;
      sBc[wq][lo] = al;
      lgkm0();
      #pragma unroll
      for (int g = 0; g < 4; ++g) {
        const f32x4 a4 = *reinterpret_cast<const f32x4*>(&sBc[wq][g * 8 + hi * 4]);
        #pragma unroll
        for (int j = 0; j < 4; ++j) {
          acc[0][g * 4 + j] *= a4[j];
          acc[1][g * 4 + j] *= a4[j];
        }
      }
    }
    // P = exp2(S' - m'), row sum  (raw v_exp_f32, no libcall, no pre-mul)
    #pragma unroll
    for (int kvb = 0; kvb < 2; ++kvb)
      #pragma unroll
      for (int r = 0; r < 16; ++r)
        st[kvb][r] = __builtin_amdgcn_exp2f(st[kvb][r] - mst);
    {
      const f32x16 sv = st[0] + st[1];
      float sum = ((sv[0] + sv[1]) + (sv[2] + sv[3])) + ((sv[4] + sv[5]) + (sv[6] + sv[7]))
                + ((sv[8] + sv[9]) + (sv[10] + sv[11])) + ((sv[12] + sv[13]) + (sv[14] + sv[15]));
      sum += __shfl_xor(sum, 32);
      lst += sum;
    }
    // pack P -> bf16 A-fragments via cvt_pk + permlane32_swap
    short8 pa[4];
    #pragma unroll
    for (int kvb = 0; kvb < 2; ++kvb)
      #pragma unroll
      for (int f = 0; f < 2; ++f) {
        uint32_t wa = pkbf(st[kvb][f * 8 + 0], st[kvb][f * 8 + 1]);
        uint32_t wb = pkbf(st[kvb][f * 8 + 2], st[kvb][f * 8 + 3]);
        uint32_t wc = pkbf(st[kvb][f * 8 + 4], st[kvb][f * 8 + 5]);
        uint32_t wd = pkbf(st[kvb][f * 8 + 6], st[kvb][f * 8 + 7]);
        asm volatile("v_permlane32_swap_b32 %0, %1" : "+v"(wa), "+v"(wc));
        asm volatile("v_permlane32_swap_b32 %0, %1" : "+v"(wb), "+v"(wd));
        union { uint32_t w[4]; short8 v; } u;
        u.w[0] = wa; u.w[1] = wb; u.w[2] = wc; u.w[3] = wd;
        pa[kvb * 2 + f] = u.v;
      }

    // O += P V  (B-operand = V^T rows d)
    #pragma unroll
    for (int db = 0; db < 2; ++db) {
      short8 vb[4];
      #pragma unroll
      for (int k4 = 0; k4 < 4; ++k4) {
        const int row = db * 32 + lo, ch = k4 * 2 + hi;
        vb[k4] = *reinterpret_cast<const short8*>(
            &sVt[cur][(row * 8 + (ch ^ (row & 7))) * 8]);
      }
      acc[db] = mfma32(pa[0], vb[0], acc[db]);
      acc[db] = mfma32(pa[1], vb[1], acc[db]);
      acc[db] = mfma32(pa[2], vb[2], acc[db]);
      acc[db] = mfma32(pa[3], vb[3], acc[db]);
    }
  }

  // epilogue: O /= l, write bf16 [8192][1024]
  sBc[wq][lo] = 1.f / lst;
  lgkm0();
  #pragma unroll
  for (int g = 0; g < 4; ++g) {
    const f32x4 r4 = *reinterpret_cast<const f32x4*>(&sBc[wq][g * 8 + hi * 4]);
    #pragma unroll
    for (int j = 0; j < 4; ++j) {
      const int qrow = q0 + wq * 32 + g * 8 + hi * 4 + j;
      #pragma unroll
      for (int db = 0; db < 2; ++db)
        outp[(size_t)(b * SEQ + qrow) * EMBED + h * 64 + db * 32 + lo] =
            f2bf(acc[db][g * 4 + j] * r4[j]);
    }
  }
}

// ---------------- launch ----------------
extern "C" void kernel_launch(void* const* d_in, const int* in_sizes, int n_in,
                              void* d_out, int out_size, void* d_ws, size_t ws_size,
                              hipStream_t stream) {
  const float* x     = (const float*)d_in[0];
  const float* ln1_g = (const float*)d_in[1];
  const float* ln1_b = (const float*)d_in[2];
  const float* qkv_w = (const float*)d_in[3];
  const float* out_w = (const float*)d_in[4];
  const float* out_b = (const float*)d_in[5];
  const float* ln2_g = (const float*)d_in[6];
  const float* ln2_b = (const float*)d_in[7];
  const float* fc1_w = (const float*)d_in[8];
  const float* fc1_b = (const float*)d_in[9];
  const float* fc2_w = (const float*)d_in[10];
  const float* fc2_b = (const float*)d_in[11];
  float* out = (float*)d_out;
  char* ws = (char*)d_ws;

  // workspace layout (bytes)
  ushort* qkvw = (ushort*)(ws);                                   //  6291456
  ushort* outw = (ushort*)(ws + 6291456);                         //  2097152
  ushort* fc1w = (ushort*)(ws + 8388608);                         //  8388608
  ushort* fc2w = (ushort*)(ws + 16777216);                        //  8388608
  float*  x1   = (float*) (ws + 25165824);                        // 33554432
  ushort* hbuf = (ushort*)(ws + 58720256);                        // 16777216
  ushort* qkbuf= (ushort*)(ws + 75497472);                        // 33554432  [8192][2048]
  ushort* vtbuf= (ushort*)(ws + 109051904);                       // 16777216  [1024][8192]
  ushort* obuf = (ushort*)(ws + 125829120);                       // 16777216
  ushort* gbuf = qkbuf;  // gelu buf [8192][4096] reuses qk+vt+o regions (64 MiB)

  // fused LN1 + all-weight conversion (independent work, one dispatch)
  ln_cvt_kernel<<<NTOK + 2048, 256, 0, stream>>>(
      x, ln1_g, ln1_b, hbuf,
      qkv_w, qkvw, 3 * EMBED * EMBED / 4,
      out_w, outw, EMBED * EMBED / 4,
      fc1_w, fc1w, HIDDEN * EMBED / 4,
      fc2_w, fc2w, EMBED * HIDDEN / 4);

  // QK: [8192][2048] = hbuf * Wqk^T   (EPI 3: Q cols scaled by log2e)
  gemm256<3, true><<<256, 512, 0, stream>>>(hbuf, qkvw, nullptr, nullptr,
                                            qkbuf, nullptr, NTOK, 2 * EMBED, EMBED, 32);
  // V^T: [1024][8192] = Wv * hbuf^T   (256x128 tiles, N-partitioned)
  gemm256<0, false><<<256, 512, 0, stream>>>(qkvw + 2048 * 1024, hbuf, nullptr, nullptr,
                                             vtbuf, nullptr, EMBED, NTOK, EMBED, 4);
  attn_kernel<<<dim3(64, 8), 512, 0, stream>>>(qkbuf, vtbuf, obuf);
  // out-proj
  gemm256<1, false><<<256, 512, 0, stream>>>(obuf, outw, out_b, x,
                                             nullptr, x1, NTOK, EMBED, EMBED, 32);
  ln_kernel<<<NTOK, 256, 0, stream>>>(x1, ln2_g, ln2_b, hbuf);
  // fc1
  gemm256<2, true><<<512, 512, 0, stream>>>(hbuf, fc1w, fc1_b, nullptr,
                                            gbuf, nullptr, NTOK, HIDDEN, EMBED, 32);
  // fc2
  gemm256<1, false><<<256, 512, 0, stream>>>(gbuf, fc2w, fc2_b, x1,
                                             nullptr, out, NTOK, EMBED, HIDDEN, 32);
}

// Round 20
// 371.567 us; speedup vs baseline: 1.0549x; 1.0108x over previous
//
#include <hip/hip_runtime.h>
#include <cstdint>

// Transformer block: LN1 -> {QK GEMM, V^T GEMM} -> flash attn (swapped-QK,
// in-register softmax exp2-domain, permlane P re-layout) -> out-proj(+res)
// -> LN2 -> fc1(+GELU) -> fc2(+res). All matmuls bf16 MFMA, fp32 accum.
// R20 = R19 + x1 residual demoted to bf16 (out-proj writes bf16, LN2 reads
// bf16, fc2 residual reads bf16): ~50 MB less HBM traffic. Everything else
// frozen at R19 (375.6 us best).

using short8 = __attribute__((ext_vector_type(8))) short;
using f32x4  = __attribute__((ext_vector_type(4))) float;
using f32x16 = __attribute__((ext_vector_type(16))) float;

#define EMBED  1024
#define HIDDEN 4096
#define SEQ    2048
#define NTOK   8192   // 4*2048
#define LOG2E  1.4426950408889634f

__device__ __forceinline__ ushort f2bf(float x) {
  union { float f; uint32_t u; } v; v.f = x;
  uint32_t r = v.u + 0x7fffu + ((v.u >> 16) & 1u);   // RNE
  return (ushort)(r >> 16);
}
__device__ __forceinline__ float b2f(ushort h) {
  union { uint32_t u; float f; } v; v.u = ((uint32_t)h) << 16;
  return v.f;
}

__device__ __forceinline__ uint32_t pkbf(float lo, float hi) {
  uint32_t r;
  asm("v_cvt_pk_bf16_f32 %0, %1, %2" : "=v"(r) : "v"(lo), "v"(hi));
  return r;
}

__device__ __forceinline__ void gload16(const void* g, void* l) {
  __builtin_amdgcn_global_load_lds((__attribute__((address_space(1))) void*)(g),
                                   (__attribute__((address_space(3))) void*)(l), 16, 0, 0);
}

template<int N> __device__ __forceinline__ void vwait() {
  asm volatile("s_waitcnt vmcnt(%0)" :: "n"(N) : "memory");
}
__device__ __forceinline__ void lgkm0() {
  asm volatile("s_waitcnt lgkmcnt(0)" ::: "memory");
}
__device__ __forceinline__ void fence_bar() {
  asm volatile("" ::: "memory");
  __builtin_amdgcn_s_barrier();
  asm volatile("" ::: "memory");
}

__device__ __forceinline__ f32x4 mfma16(short8 a, short8 b, f32x4 c) {
  return __builtin_amdgcn_mfma_f32_16x16x32_bf16(a, b, c, 0, 0, 0);
}
__device__ __forceinline__ f32x16 mfma32(short8 a, short8 b, f32x16 c) {
  return __builtin_amdgcn_mfma_f32_32x32x16_bf16(a, b, c, 0, 0, 0);
}
__device__ __forceinline__ f32x16 zero16() {
  f32x16 z = {0.f,0.f,0.f,0.f,0.f,0.f,0.f,0.f,0.f,0.f,0.f,0.f,0.f,0.f,0.f,0.f};
  return z;
}

// ---------------- LN row body (fp32 input) ----------------
__device__ __forceinline__ void ln_row(const float* __restrict__ x,
                                       const float* __restrict__ g,
                                       const float* __restrict__ b,
                                       ushort* __restrict__ out, int row, int tid) {
  const float4 xv = reinterpret_cast<const float4*>(x + (size_t)row * EMBED)[tid];
  float s  = xv.x + xv.y + xv.z + xv.w;
  float s2 = xv.x*xv.x + xv.y*xv.y + xv.z*xv.z + xv.w*xv.w;
  #pragma unroll
  for (int off = 32; off >= 1; off >>= 1) { s += __shfl_xor(s, off); s2 += __shfl_xor(s2, off); }
  __shared__ float ps[4], ps2[4];
  if ((tid & 63) == 0) { ps[tid >> 6] = s; ps2[tid >> 6] = s2; }
  __syncthreads();
  s  = ps[0] + ps[1] + ps[2] + ps[3];
  s2 = ps2[0] + ps2[1] + ps2[2] + ps2[3];
  const float mu  = s * (1.f / EMBED);
  const float var = s2 * (1.f / EMBED) - mu * mu;
  const float rs  = rsqrtf(var + 1e-5f);
  const float4 gv = reinterpret_cast<const float4*>(g)[tid];
  const float4 bv = reinterpret_cast<const float4*>(b)[tid];
  ushort4 o;
  o.x = f2bf((xv.x - mu) * rs * gv.x + bv.x);
  o.y = f2bf((xv.y - mu) * rs * gv.y + bv.y);
  o.z = f2bf((xv.z - mu) * rs * gv.z + bv.z);
  o.w = f2bf((xv.w - mu) * rs * gv.w + bv.w);
  reinterpret_cast<ushort4*>(out + (size_t)row * EMBED)[tid] = o;
}

// ---------------- fused: LN1 (blocks 0..8191) + weight cvt (blocks 8192..10239) ----------------
__global__ __launch_bounds__(256) void ln_cvt_kernel(const float* __restrict__ x,
                                                     const float* __restrict__ ln_g,
                                                     const float* __restrict__ ln_b,
                                                     ushort* __restrict__ hout,
                                                     const float* __restrict__ s0, ushort* __restrict__ d0, int n0,
                                                     const float* __restrict__ s1, ushort* __restrict__ d1, int n1,
                                                     const float* __restrict__ s2, ushort* __restrict__ d2, int n2,
                                                     const float* __restrict__ s3, ushort* __restrict__ d3, int n3) {
  const int tid = threadIdx.x;
  if (blockIdx.x < NTOK) {
    ln_row(x, ln_g, ln_b, hout, blockIdx.x, tid);
    return;
  }
  const int cb = blockIdx.x - NTOK;               // 0..2047
  const int total = n0 + n1 + n2 + n3;
  for (int i = cb * 256 + tid; i < total; i += 2048 * 256) {
    const float* s; ushort* d; int j = i;
    if (j < n0) { s = s0; d = d0; }
    else {
      j -= n0;
      if (j < n1) { s = s1; d = d1; }
      else {
        j -= n1;
        if (j < n2) { s = s2; d = d2; }
        else { j -= n2; s = s3; d = d3; }
      }
    }
    const float4 v = reinterpret_cast<const float4*>(s)[j];
    ushort4 o; o.x = f2bf(v.x); o.y = f2bf(v.y); o.z = f2bf(v.z); o.w = f2bf(v.w);
    reinterpret_cast<ushort4*>(d)[j] = o;
  }
}

// ---------------- LayerNorm, bf16 input (LN2 over bf16 x1) ----------------
__global__ __launch_bounds__(256) void lnb_kernel(const ushort* __restrict__ x,
                                                  const float* __restrict__ g,
                                                  const float* __restrict__ b,
                                                  ushort* __restrict__ out) {
  const int row = blockIdx.x, tid = threadIdx.x;
  const ushort4 xu = reinterpret_cast<const ushort4*>(x + (size_t)row * EMBED)[tid];
  float4 xv;
  xv.x = b2f(xu.x); xv.y = b2f(xu.y); xv.z = b2f(xu.z); xv.w = b2f(xu.w);
  float s  = xv.x + xv.y + xv.z + xv.w;
  float s2 = xv.x*xv.x + xv.y*xv.y + xv.z*xv.z + xv.w*xv.w;
  #pragma unroll
  for (int off = 32; off >= 1; off >>= 1) { s += __shfl_xor(s, off); s2 += __shfl_xor(s2, off); }
  __shared__ float ps[4], ps2[4];
  if ((tid & 63) == 0) { ps[tid >> 6] = s; ps2[tid >> 6] = s2; }
  __syncthreads();
  s  = ps[0] + ps[1] + ps[2] + ps[3];
  s2 = ps2[0] + ps2[1] + ps2[2] + ps2[3];
  const float mu  = s * (1.f / EMBED);
  const float var = s2 * (1.f / EMBED) - mu * mu;
  const float rs  = rsqrtf(var + 1e-5f);
  const float4 gv = reinterpret_cast<const float4*>(g)[tid];
  const float4 bv = reinterpret_cast<const float4*>(b)[tid];
  ushort4 o;
  o.x = f2bf((xv.x - mu) * rs * gv.x + bv.x);
  o.y = f2bf((xv.y - mu) * rs * gv.y + bv.y);
  o.z = f2bf((xv.z - mu) * rs * gv.z + bv.z);
  o.w = f2bf((xv.w - mu) * rs * gv.w + bv.w);
  reinterpret_cast<ushort4*>(out + (size_t)row * EMBED)[tid] = o;
}

// ---------------- bf16 GEMM: C[M,N] = A[M,K] * B[N,K]^T (+epilogue) ----------------
// SQ=true: 256x256 tile (8 waves 2Mx4N). SQ=false: 256x128 tile (8 waves 4Mx2N).
// Quad-buffered BK=32 tiles; stage tile u+3 during tile u; counted vmcnt;
// x4 unroll; ONE vwait+barrier per tile. L2-locality XCD partition.
// EPI: 0 bf16 | 2 bf16 gelu(acc+bias) | 3 bf16, cols<1024 * log2e
//      4 bf16(acc+bias+resf)  [out-proj]  | 5 fp32 acc+bias+b2f(resb) [fc2]
template<int EPI, bool SQ>
__global__ __launch_bounds__(512) void gemm256(const ushort* __restrict__ A,
                                               const ushort* __restrict__ B,
                                               const float* __restrict__ bias,
                                               const float* __restrict__ resf,
                                               const ushort* __restrict__ resb,
                                               ushort* __restrict__ outb,
                                               float* __restrict__ outf,
                                               int M, int N, int K, int gx) {
  constexpr int BN   = SQ ? 256 : 128;
  constexpr int MP   = SQ ? 8 : 4;          // 16-row m-positions per wave
  constexpr int NPH  = SQ ? 2 : 1;          // phases per K-tile
  constexpr int LPT  = SQ ? 4 : 3;          // gload16 rounds per tile per thread
  constexpr int NB   = LPT - 2;             // B staging rounds
  constexpr int ABUF = 256 * 32;            // ushorts
  constexpr int BBUF = BN * 32;
  __shared__ ushort lds[4][ABUF + BBUF];

  const int nwg = gridDim.x;                // nwg % 8 == 0 for all our shapes
  const int b0  = blockIdx.x;
  // locality partition (XCD = blockIdx % 8)
  const int p = b0 & 7, li = b0 >> 3;
  int mt, nt;
  if ((gx & 7) == 0) {                      // partition M across XCDs
    const int g = gx >> 3;                  // m-tiles per XCD
    mt = p * g + (li % g);                  // m fastest within XCD
    nt = li / g;
  } else {                                  // partition N across XCDs (gy%8==0)
    const int g = (nwg / gx) >> 3;          // n-tiles per XCD
    nt = p * g + (li % g);                  // n fastest within XCD
    mt = li / g;
  }
  const int m0 = mt * 256;
  const int n0 = nt * BN;

  const int tid = threadIdx.x, lane = tid & 63, wave = tid >> 6;
  const int wm = (SQ ? (wave >> 2) : (wave >> 1)) * (MP * 16);
  const int wn = (SQ ? (wave & 3) : (wave & 1)) * 64;
  const int l15 = lane & 15, l4 = lane >> 4;
  const int NT = K >> 5;                    // divisible by 4 for all our shapes

  // per-thread staging source pointers; advance +32 elems per staged tile
  const ushort* aSrc[2];
  const ushort* bSrc[NB];
  #pragma unroll
  for (int rd = 0; rd < 2; ++rd) {
    const int slot = rd * 512 + tid;
    const int r = slot >> 2;
    const int cs = (slot & 3) ^ ((r >> 1) & 3);
    aSrc[rd] = A + (size_t)(m0 + r) * K + cs * 8;
  }
  #pragma unroll
  for (int rd = 0; rd < NB; ++rd) {
    const int slot = rd * 512 + tid;
    const int r = slot >> 2;
    const int cs = (slot & 3) ^ ((r >> 1) & 3);
    bSrc[rd] = B + (size_t)(n0 + r) * K + cs * 8;
  }
  auto stageA = [&](int buf, int rd) { gload16(aSrc[rd], &lds[buf][(rd * 512 + tid) * 8]); };
  auto stageB = [&](int buf, int rd) { gload16(bSrc[rd], &lds[buf][ABUF + (rd * 512 + tid) * 8]); };
  auto advance = [&]() {
    #pragma unroll
    for (int rd = 0; rd < 2; ++rd) aSrc[rd] += 32;
    #pragma unroll
    for (int rd = 0; rd < NB; ++rd) bSrc[rd] += 32;
  };

  // prologue: stage tiles 0..2 into bufs 0..2
  #pragma unroll
  for (int t = 0; t < 3; ++t) {
    stageA(t, 0); stageA(t, 1);
    #pragma unroll
    for (int rd = 0; rd < NB; ++rd) stageB(t, rd);
    advance();
  }
  vwait<2 * LPT>();               // tile 0 resident; 2 tiles stay in flight
  fence_bar();

  f32x4 acc[MP][4] = {};

  // one K-tile; q = buffer index (compile-time at every call site),
  // st = stage tile u+3, wsel: 0 -> vwait(2LPT), 1 -> vwait(LPT), 2 -> vwait(0), 3 -> none
  // Single sync point per tile: vwait + barrier at the tile boundary.
  auto doTile = [&](int q, bool st, int wsel) {
    const ushort* bA = &lds[q][0];
    const ushort* bB = &lds[q][ABUF];
    const int sbuf = (q + 3) & 3;
    short8 bf[4];
    #pragma unroll
    for (int j = 0; j < 4; ++j) {
      const int rb = wn + j * 16 + l15;
      bf[j] = *reinterpret_cast<const short8*>(&bB[rb * 32 + ((l4 ^ ((rb >> 1) & 3)) * 8)]);
    }
    #pragma unroll
    for (int ph = 0; ph < NPH; ++ph) {
      short8 af[4];
      #pragma unroll
      for (int i = 0; i < 4; ++i) {
        const int ra = wm + (ph * 4 + i) * 16 + l15;
        af[i] = *reinterpret_cast<const short8*>(&bA[ra * 32 + ((l4 ^ ((ra >> 1) & 3)) * 8)]);
      }
      if (st) {
        if constexpr (SQ) {
          if (ph == 0) { stageA(sbuf, 0); stageA(sbuf, 1); }
          else         { stageB(sbuf, 0); stageB(sbuf, 1); }
        } else {
          stageA(sbuf, 0); stageA(sbuf, 1); stageB(sbuf, 0);
        }
      }
      __builtin_amdgcn_s_setprio(1);
      #pragma unroll
      for (int i = 0; i < 4; ++i)
        #pragma unroll
        for (int j = 0; j < 4; ++j)
          acc[ph * 4 + i][j] = mfma16(af[i], bf[j], acc[ph * 4 + i][j]);
      __builtin_amdgcn_s_setprio(0);
    }
    if (st) advance();
    if (wsel == 0)      vwait<2 * LPT>();   // next tile's data resident
    else if (wsel == 1) vwait<LPT>();
    else if (wsel == 2) vwait<0>();
    fence_bar();
  };

  for (int u0 = 0; u0 < NT - 4; u0 += 4) {
    doTile(0, true, 0); doTile(1, true, 0); doTile(2, true, 0); doTile(3, true, 0);
  }
  // tail: u = NT-4 .. NT-1
  doTile(0, true, 0); doTile(1, false, 1); doTile(2, false, 2); doTile(3, false, 3);

  #pragma unroll
  for (int i = 0; i < MP; ++i)
    #pragma unroll
    for (int j = 0; j < 4; ++j)
      #pragma unroll
      for (int r = 0; r < 4; ++r) {
        const int row = m0 + wm + i * 16 + l4 * 4 + r;
        const int col = n0 + wn + j * 16 + l15;
        const size_t idx = (size_t)row * N + col;
        float v = acc[i][j][r];
        if constexpr (EPI == 0) {
          outb[idx] = f2bf(v);
        } else if constexpr (EPI == 2) {
          v += bias[col];
          v = 0.5f * v * (1.f + erff(v * 0.70710678118654752f));
          outb[idx] = f2bf(v);
        } else if constexpr (EPI == 3) {
          // scale Q columns (col < 1024) by log2e for exp2-domain softmax
          outb[idx] = f2bf((col < 1024) ? v * LOG2E : v);
        } else if constexpr (EPI == 4) {
          // out-proj: bf16 residual output (x1b = acc + bias + x)
          outb[idx] = f2bf(v + bias[col] + resf[idx]);
        } else {
          // fc2: fp32 final output = acc + bias + bf16 residual
          outf[idx] = v + bias[col] + b2f(resb[idx]);
        }
      }
}

// ---------------- flash attention, swapped-QK, exp2-domain softmax ----------------
// grid (B*H=64, SEQ/256=8), block 512 (8 waves). Wave: 32 q rows.
// qk: [8192][2048] bf16 (q*log2e at col h*64, k at col 1024+h*64).
// vt: [1024][8192] bf16. S' = S*log2e -> P = exp2(S'-m') via raw v_exp_f32.
// No 1/sqrt(d) scaling (per reference). 16 waves/CU.
#define KVB 64
#define NTT (SEQ / KVB)

__global__ __launch_bounds__(512, 4) void attn_kernel(const ushort* __restrict__ qk,
                                                      const ushort* __restrict__ vt,
                                                      ushort* __restrict__ outp) {
  const int tid = threadIdx.x, lane = tid & 63, wq = tid >> 6;   // wq 0..7
  const int hi = lane >> 5, lo = lane & 31;
  const int b = blockIdx.x >> 4, h = blockIdx.x & 15;
  const int q0 = blockIdx.y * 256;

  __shared__ ushort sK[2][64 * 64];
  __shared__ ushort sVt[2][64 * 64];
  __shared__ float sBc[8][32];

  // Q fragments (B-operand): wave covers q rows q0 + wq*32 .. +31 (lane q = lo)
  short8 qf[4];
  #pragma unroll
  for (int kc = 0; kc < 4; ++kc)
    qf[kc] = *reinterpret_cast<const short8*>(
        qk + (size_t)(b * SEQ + q0 + wq * 32 + lo) * 2048 + h * 64 + kc * 16 + hi * 8);

  auto STAGE = [&](int bb, int kt) {
    const int r = tid >> 3;
    const int c = (tid & 7) ^ (r & 7);            // inverse-swizzled source chunk
    gload16(qk + (size_t)(b * SEQ + kt + r) * 2048 + 1024 + h * 64 + c * 8,
            &sK[bb][wq * 64 * 8]);                // wave-uniform dest + lane*16B
    gload16(vt + (size_t)(h * 64 + r) * 8192 + b * SEQ + kt + c * 8,
            &sVt[bb][wq * 64 * 8]);
  };

  f32x16 acc[2];
  acc[0] = zero16(); acc[1] = zero16();
  float mst = -1e30f, lst = 0.f;

  STAGE(0, 0);
  for (int t = 0; t < NTT; ++t) {
    const int cur = t & 1;
    __syncthreads();                       // staged buf[cur] ready; buf[cur^1] free
    if (t + 1 < NTT) STAGE(cur ^ 1, (t + 1) * KVB);

    // K fragments (A-operand): row kv, swizzled b128 reads
    short8 kf[2][4];
    #pragma unroll
    for (int kvb = 0; kvb < 2; ++kvb)
      #pragma unroll
      for (int kc = 0; kc < 4; ++kc) {
        const int row = kvb * 32 + lo, ch = kc * 2 + hi;
        kf[kvb][kc] = *reinterpret_cast<const short8*>(
            &sK[cur][(row * 8 + (ch ^ (row & 7))) * 8]);
      }

    // S'^T = K * (Q*log2e)^T : lane holds q=lo, kv rows in regs (exp2 domain)
    f32x16 st[2];
    #pragma unroll
    for (int kvb = 0; kvb < 2; ++kvb) {
      f32x16 tq = zero16();
      tq = mfma32(kf[kvb][0], qf[0], tq);
      tq = mfma32(kf[kvb][1], qf[1], tq);
      tq = mfma32(kf[kvb][2], qf[2], tq);
      tq = mfma32(kf[kvb][3], qf[3], tq);
      st[kvb] = tq;
    }
    // row max: pairwise combine + max3-fusable triple chain
    f32x16 mm;
    #pragma unroll
    for (int r = 0; r < 16; ++r) mm[r] = fmaxf(st[0][r], st[1][r]);
    float pm = fmaxf(fmaxf(mm[0], mm[1]), mm[2]);
    pm = fmaxf(fmaxf(pm, mm[3]), mm[4]);
    pm = fmaxf(fmaxf(pm, mm[5]), mm[6]);
    pm = fmaxf(fmaxf(pm, mm[7]), mm[8]);
    pm = fmaxf(fmaxf(pm, mm[9]), mm[10]);
    pm = fmaxf(fmaxf(pm, mm[11]), mm[12]);
    pm = fmaxf(fmaxf(pm, mm[13]), mm[14]);
    pm = fmaxf(pm, mm[15]);
    pm = fmaxf(pm, __shfl_xor(pm, 32));
    // defer-max (exp2 domain): 8 nats = 11.54 bits
    if (__any(pm > mst + 11.54f)) {
      const float mn = fmaxf(mst, pm);
      const float al = __builtin_amdgcn_exp2f(mst - mn);
      mst = mn; lst *= al;
      sBc[wq][lo] = al;
      lgkm0();
      #pragma unroll
      for (int g = 0; g < 4; ++g) {
        const f32x4 a4 = *reinterpret_cast<const f32x4*>(&sBc[wq][g * 8 + hi * 4]);
        #pragma unroll
        for (int j = 0; j < 4; ++j) {
          acc[0][g * 4 + j] *= a4[j];
          acc[1][g * 4 + j] *= a4[j];
        }
      }
    }
    // P = exp2(S' - m'), row sum  (raw v_exp_f32, no libcall, no pre-mul)
    #pragma unroll
    for (int kvb = 0; kvb < 2; ++kvb)
      #pragma unroll
      for (int r = 0; r < 16; ++r)
        st[kvb][r] = __builtin_amdgcn_exp2f(st[kvb][r] - mst);
    {
      const f32x16 sv = st[0] + st[1];
      float sum = ((sv[0] + sv[1]) + (sv[2] + sv[3])) + ((sv[4] + sv[5]) + (sv[6] + sv[7]))
                + ((sv[8] + sv[9]) + (sv[10] + sv[11])) + ((sv[12] + sv[13]) + (sv[14] + sv[15]));
      sum += __shfl_xor(sum, 32);
      lst += sum;
    }
    // pack P -> bf16 A-fragments via cvt_pk + permlane32_swap
    short8 pa[4];
    #pragma unroll
    for (int kvb = 0; kvb < 2; ++kvb)
      #pragma unroll
      for (int f = 0; f < 2; ++f) {
        uint32_t wa = pkbf(st[kvb][f * 8 + 0], st[kvb][f * 8 + 1]);
        uint32_t wb = pkbf(st[kvb][f * 8 + 2], st[kvb][f * 8 + 3]);
        uint32_t wc = pkbf(st[kvb][f * 8 + 4], st[kvb][f * 8 + 5]);
        uint32_t wd = pkbf(st[kvb][f * 8 + 6], st[kvb][f * 8 + 7]);
        asm volatile("v_permlane32_swap_b32 %0, %1" : "+v"(wa), "+v"(wc));
        asm volatile("v_permlane32_swap_b32 %0, %1" : "+v"(wb), "+v"(wd));
        union { uint32_t w[4]; short8 v; } u;
        u.w[0] = wa; u.w[1] = wb; u.w[2] = wc; u.w[3] = wd;
        pa[kvb * 2 + f] = u.v;
      }

    // O += P V  (B-operand = V^T rows d)
    #pragma unroll
    for (int db = 0; db < 2; ++db) {
      short8 vb[4];
      #pragma unroll
      for (int k4 = 0; k4 < 4; ++k4) {
        const int row = db * 32 + lo, ch = k4 * 2 + hi;
        vb[k4] = *reinterpret_cast<const short8*>(
            &sVt[cur][(row * 8 + (ch ^ (row & 7))) * 8]);
      }
      acc[db] = mfma32(pa[0], vb[0], acc[db]);
      acc[db] = mfma32(pa[1], vb[1], acc[db]);
      acc[db] = mfma32(pa[2], vb[2], acc[db]);
      acc[db] = mfma32(pa[3], vb[3], acc[db]);
    }
  }

  // epilogue: O /= l, write bf16 [8192][1024]
  sBc[wq][lo] = 1.f / lst;
  lgkm0();
  #pragma unroll
  for (int g = 0; g < 4; ++g) {
    const f32x4 r4 = *reinterpret_cast<const f32x4*>(&sBc[wq][g * 8 + hi * 4]);
    #pragma unroll
    for (int j = 0; j < 4; ++j) {
      const int qrow = q0 + wq * 32 + g * 8 + hi * 4 + j;
      #pragma unroll
      for (int db = 0; db < 2; ++db)
        outp[(size_t)(b * SEQ + qrow) * EMBED + h * 64 + db * 32 + lo] =
            f2bf(acc[db][g * 4 + j] * r4[j]);
    }
  }
}

// ---------------- launch ----------------
extern "C" void kernel_launch(void* const* d_in, const int* in_sizes, int n_in,
                              void* d_out, int out_size, void* d_ws, size_t ws_size,
                              hipStream_t stream) {
  const float* x     = (const float*)d_in[0];
  const float* ln1_g = (const float*)d_in[1];
  const float* ln1_b = (const float*)d_in[2];
  const float* qkv_w = (const float*)d_in[3];
  const float* out_w = (const float*)d_in[4];
  const float* out_b = (const float*)d_in[5];
  const float* ln2_g = (const float*)d_in[6];
  const float* ln2_b = (const float*)d_in[7];
  const float* fc1_w = (const float*)d_in[8];
  const float* fc1_b = (const float*)d_in[9];
  const float* fc2_w = (const float*)d_in[10];
  const float* fc2_b = (const float*)d_in[11];
  float* out = (float*)d_out;
  char* ws = (char*)d_ws;

  // workspace layout (bytes)
  ushort* qkvw = (ushort*)(ws);                                   //  6291456
  ushort* outw = (ushort*)(ws + 6291456);                         //  2097152
  ushort* fc1w = (ushort*)(ws + 8388608);                         //  8388608
  ushort* fc2w = (ushort*)(ws + 16777216);                        //  8388608
  ushort* x1b  = (ushort*)(ws + 25165824);                        // 16777216  [8192][1024] bf16
  ushort* hbuf = (ushort*)(ws + 58720256);                        // 16777216
  ushort* qkbuf= (ushort*)(ws + 75497472);                        // 33554432  [8192][2048]
  ushort* vtbuf= (ushort*)(ws + 109051904);                       // 16777216  [1024][8192]
  ushort* obuf = (ushort*)(ws + 125829120);                       // 16777216
  ushort* gbuf = qkbuf;  // gelu buf [8192][4096] reuses qk+vt+o regions (64 MiB)

  // fused LN1 + all-weight conversion (independent work, one dispatch)
  ln_cvt_kernel<<<NTOK + 2048, 256, 0, stream>>>(
      x, ln1_g, ln1_b, hbuf,
      qkv_w, qkvw, 3 * EMBED * EMBED / 4,
      out_w, outw, EMBED * EMBED / 4,
      fc1_w, fc1w, HIDDEN * EMBED / 4,
      fc2_w, fc2w, EMBED * HIDDEN / 4);

  // QK: [8192][2048] = hbuf * Wqk^T   (EPI 3: Q cols scaled by log2e)
  gemm256<3, true><<<256, 512, 0, stream>>>(hbuf, qkvw, nullptr, nullptr, nullptr,
                                            qkbuf, nullptr, NTOK, 2 * EMBED, EMBED, 32);
  // V^T: [1024][8192] = Wv * hbuf^T   (256x128 tiles, N-partitioned)
  gemm256<0, false><<<256, 512, 0, stream>>>(qkvw + 2048 * 1024, hbuf, nullptr, nullptr, nullptr,
                                             vtbuf, nullptr, EMBED, NTOK, EMBED, 4);
  attn_kernel<<<dim3(64, 8), 512, 0, stream>>>(qkbuf, vtbuf, obuf);
  // out-proj: x1b (bf16) = obuf @ outw^T + out_b + x
  gemm256<4, false><<<256, 512, 0, stream>>>(obuf, outw, out_b, x, nullptr,
                                             x1b, nullptr, NTOK, EMBED, EMBED, 32);
  lnb_kernel<<<NTOK, 256, 0, stream>>>(x1b, ln2_g, ln2_b, hbuf);
  // fc1
  gemm256<2, true><<<512, 512, 0, stream>>>(hbuf, fc1w, fc1_b, nullptr, nullptr,
                                            gbuf, nullptr, NTOK, HIDDEN, EMBED, 32);
  // fc2: out (fp32) = gbuf @ fc2w^T + fc2_b + x1b
  gemm256<5, false><<<256, 512, 0, stream>>>(gbuf, fc2w, fc2_b, nullptr, x1b,
                                             nullptr, out, NTOK, EMBED, HIDDEN, 32);
}